// Round 11
// baseline (2691.788 us; speedup 1.0000x reference)
//
#include <hip/hip_runtime.h>
#include <stdint.h>

#define SS 512
#define BB 64
#define HH 256
#define TT 32

typedef __attribute__((ext_vector_type(8))) short bf16x8;
typedef __attribute__((ext_vector_type(4))) short short4v;
typedef __attribute__((ext_vector_type(4))) float f32x4;

__device__ __forceinline__ unsigned short f2bf(float f){
  unsigned u = __float_as_uint(f);
  unsigned r = (u + 0x7FFFu + ((u >> 16) & 1u)) >> 16;
  return (unsigned short)r;
}
__device__ __forceinline__ float bf2f(unsigned short s){
  return __uint_as_float(((unsigned)s) << 16);
}
__device__ __forceinline__ float sigm(float x){ return 1.0f/(1.0f+__expf(-x)); }
__device__ __forceinline__ float ftanh(float x){
  float e = __expf(2.f*x);
  return 1.f - 2.f/(e + 1.f);
}
__device__ __forceinline__ unsigned cvt4fp8(float a0, float a1, float a2, float a3){
  int d = __builtin_amdgcn_cvt_pk_fp8_f32(a0, a1, 0, false);
  d = __builtin_amdgcn_cvt_pk_fp8_f32(a2, a3, d, true);
  return (unsigned)d;
}
__device__ __forceinline__ unsigned short cvt2fp8(float a0, float a1){
  int d = __builtin_amdgcn_cvt_pk_fp8_f32(a0, a1, 0, false);
  return (unsigned short)(d & 0xFFFF);
}

// swizzled-LDS fragment read (used by k_xgemm only)
__device__ __forceinline__ bf16x8 afrag(const unsigned short* A, int mt, int ktp, int nl, int kq){
  int m = mt*16 + nl;
  int sw = (m & 7) << 3;
  int kk = ktp*32 + kq*4;
  short4v lo = *(const short4v*)(A + (m << 8) + (kk ^ sw));
  short4v hi = *(const short4v*)(A + (m << 8) + ((kk + 16) ^ sw));
  bf16x8 r = {lo[0],lo[1],lo[2],lo[3],hi[0],hi[1],hi[2],hi[3]};
  return r;
}

// ---------------- fused gather + x@Wih^T GEMM (+bias fold) -> gx bf16 [dir*16+bg][t][col][b4] ----------------
__global__ __launch_bounds__(256,1) void k_xgemm(
    const int* __restrict__ seq, const float* __restrict__ emb,
    const float* __restrict__ Wih_f, const float* __restrict__ Wih_b,
    const float* __restrict__ bih_f, const float* __restrict__ bhh_f,
    const float* __restrict__ bih_b, const float* __restrict__ bhh_b,
    unsigned short* __restrict__ gx)
{
  __shared__ __align__(16) unsigned short A_l[128*256];  // 64 KiB
  __shared__ __align__(16) unsigned short B_l[64*256];   // 32 KiB

  const int tid = threadIdx.x;
  const int lane = tid & 63, w = tid >> 6;
  const int nl = lane & 15, kq = lane >> 4;
  const int pbase = blockIdx.x * 128;
  const int dir = blockIdx.y;
  const float* Wih  = dir ? Wih_b : Wih_f;
  const float* bihd = dir ? bih_b : bih_f;
  const float* bhhd = dir ? bhh_b : bhh_f;

#pragma unroll
  for (int i = 0; i < 16; ++i){
    int c = tid + i*256;
    int m = c >> 5, k8 = c & 31;
    int p = pbase + m, t = p >> 6, b = p & 63;
    int er = seq[b*SS + t];
    const float* s = emb + (size_t)er*HH + k8*8;
    float4 x0 = *(const float4*)s, x1 = *(const float4*)(s+4);
    union { unsigned short u[8]; uint4 v; } o;
    o.u[0]=f2bf(x0.x); o.u[1]=f2bf(x0.y); o.u[2]=f2bf(x0.z); o.u[3]=f2bf(x0.w);
    o.u[4]=f2bf(x1.x); o.u[5]=f2bf(x1.y); o.u[6]=f2bf(x1.z); o.u[7]=f2bf(x1.w);
    *(uint4*)&A_l[(m << 8) + ((k8*8) ^ ((m & 7) << 3))] = o.v;
  }

  for (int nb = 0; nb < 16; ++nb){
    __syncthreads();
#pragma unroll
    for (int i = 0; i < 8; ++i){
      int c = tid + i*256;
      int m = c >> 5, k8 = c & 31;
      const float* s = Wih + (size_t)(nb*64 + m)*HH + k8*8;
      float4 x0 = *(const float4*)s, x1 = *(const float4*)(s+4);
      union { unsigned short u[8]; uint4 v; } o;
      o.u[0]=f2bf(x0.x); o.u[1]=f2bf(x0.y); o.u[2]=f2bf(x0.z); o.u[3]=f2bf(x0.w);
      o.u[4]=f2bf(x1.x); o.u[5]=f2bf(x1.y); o.u[6]=f2bf(x1.z); o.u[7]=f2bf(x1.w);
      *(uint4*)&B_l[(m << 8) + ((k8*8) ^ ((m & 7) << 3))] = o.v;
    }
    __syncthreads();

    f32x4 acc[2][4];
#pragma unroll
    for (int mt = 0; mt < 2; ++mt)
#pragma unroll
      for (int nt = 0; nt < 4; ++nt) acc[mt][nt] = (f32x4){0.f,0.f,0.f,0.f};

#pragma unroll
    for (int kt = 0; kt < 8; ++kt){
      bf16x8 a0 = afrag(A_l, w*2+0, kt, nl, kq);
      bf16x8 a1 = afrag(A_l, w*2+1, kt, nl, kq);
#pragma unroll
      for (int nt = 0; nt < 4; ++nt){
        bf16x8 bv = afrag(B_l, nt, kt, nl, kq);
        acc[0][nt] = __builtin_amdgcn_mfma_f32_16x16x32_bf16(a0, bv, acc[0][nt], 0,0,0);
        acc[1][nt] = __builtin_amdgcn_mfma_f32_16x16x32_bf16(a1, bv, acc[1][nt], 0,0,0);
      }
    }

#pragma unroll
    for (int mt = 0; mt < 2; ++mt)
#pragma unroll
      for (int nt = 0; nt < 4; ++nt){
        int p0 = pbase + w*32 + mt*16 + kq*4;
        int t = p0 >> 6, b0 = p0 & 63;
        int col = nb*64 + nt*16 + nl;
        float bs = bihd[col] + bhhd[col];      // bias folded into gx
        union { unsigned short u[4]; uint2 v; } o;
        o.u[0]=f2bf(acc[mt][nt][0] + bs); o.u[1]=f2bf(acc[mt][nt][1] + bs);
        o.u[2]=f2bf(acc[mt][nt][2] + bs); o.u[3]=f2bf(acc[mt][nt][3] + bs);
        *(uint2*)(gx + ((size_t)(dir*16 + (b0 >> 2))*SS + t)*4096 + col*4) = o.v;
      }
  }
}

// ---------------- LSTM: 16 blocks, TWO independent 4-batch groups per block ----------------
// Block: dir = blk>>3, bp = blk&7 -> groups bg = 2bp (A), 2bp+1 (B), shared fp8 weights.
// Per iter: MFMA(A) -> xchA -> MFMA(B) (overlaps combine(A) VALU) -> combine(A) -> xchB -> combine(B).
// Combine lane = (batch kq, adjacent col pair 2nl..2nl+1): conflict-free b16 h8 writes, b32 h store.
#define WSC 64.0f
#define HSC 16.0f
#define ISC (1.0f/(WSC*HSC))

__global__ __launch_bounds__(512,1) void k_lstm(
    const unsigned short* __restrict__ gx,
    const float* __restrict__ Whh_f, const float* __restrict__ Whh_b,
    unsigned short* __restrict__ hf, unsigned short* __restrict__ hb)
{
  __shared__ __align__(16) unsigned char h8[2][2][16][272];  // [group][buf][row][bytes] 17 KB
  __shared__ __align__(16) float xchA[8][4][2][16][4];       // 16 KB
  __shared__ __align__(16) float xchB[8][4][2][16][4];       // 16 KB

  const int tid  = threadIdx.x;
  const int lane = tid & 63;
  const int w    = tid >> 6;
  const int nl   = lane & 15;
  const int kq   = lane >> 4;
  const int dir  = blockIdx.x >> 3;
  const int bp   = blockIdx.x & 7;
  const int bgA  = bp*2, bgB = bp*2 + 1;

  const float* Whh = dir ? Whh_b : Whh_f;
  unsigned short* hbuf = dir ? hb : hf;
  const unsigned short* gpA0 = gx + (size_t)(dir*16 + bgA)*SS*4096;
  const unsigned short* gpB0 = gx + (size_t)(dir*16 + bgB)*SS*4096;

  // shared fp8 Whh B-fragments (one copy serves both groups)
  long wB[4][2][8];
#pragma unroll
  for (int g = 0; g < 4; ++g)
#pragma unroll
    for (int q = 0; q < 2; ++q)
#pragma unroll
      for (int kt = 0; kt < 8; ++kt){
        int ncol = g*256 + w*32 + q*16 + nl;
        const float* p = Whh + (size_t)ncol*HH + kt*32 + kq*4;
        float4 lo = *(const float4*)p;
        float4 hi = *(const float4*)(p + 16);
        union { unsigned d[2]; long l; } u;
        u.d[0] = cvt4fp8(lo.x*WSC, lo.y*WSC, lo.z*WSC, lo.w*WSC);
        u.d[1] = cvt4fp8(hi.x*WSC, hi.y*WSC, hi.z*WSC, hi.w*WSC);
        wB[g][q][kt] = u.l;
      }

  // combine mapping: batch kq, adjacent cols c0, c0+1
  const int c0  = w*32 + 2*nl;
  const int q0  = nl >> 3;
  const int nx0 = (2*nl) & 15, nx1 = (2*nl + 1) & 15;
  const int hb8 = ((c0 & 15) >> 2)*8 + ((c0 & 16) ? 4 : 0) + (c0 & 3);  // byte off within w-block
  const int hbyte = w*32 + hb8;

  for (int i = tid; i < 4352; i += 512) ((unsigned*)h8)[i] = 0;
  __syncthreads();

  float cA[2] = {0.f,0.f}, cB[2] = {0.f,0.f};

  unsigned short gxcA[4][2], gxcB[4][2], gxnA[4][2], gxnB[4][2];
  {
    const int t0 = dir ? (SS-1) : 0;
#pragma unroll
    for (int g = 0; g < 4; ++g)
#pragma unroll
      for (int j = 0; j < 2; ++j){
        gxcA[g][j] = gpA0[((size_t)t0*4096) + (g*256 + c0 + j)*4 + kq];
        gxcB[g][j] = gpB0[((size_t)t0*4096) + (g*256 + c0 + j)*4 + kq];
      }
  }

  for (int s = 0; s < SS; ++s){
    const int t = dir ? (SS-1-s) : s;

    // prefetch next-step gx for both groups (retires under MFMA)
    {
      int sn = s + 1;
      int tn = (sn < SS) ? (dir ? (SS-1-sn) : sn) : t;
#pragma unroll
      for (int g = 0; g < 4; ++g)
#pragma unroll
        for (int j = 0; j < 2; ++j){
          gxnA[g][j] = gpA0[((size_t)tn*4096) + (g*256 + c0 + j)*4 + kq];
          gxnB[g][j] = gpB0[((size_t)tn*4096) + (g*256 + c0 + j)*4 + kq];
        }
    }

    // A-fragments for both groups from current buffers
    const unsigned char* tA = &h8[0][s & 1][0][0];
    const unsigned char* tB = &h8[1][s & 1][0][0];
    long afA[8], afB[8];
#pragma unroll
    for (int kt = 0; kt < 8; ++kt){
      afA[kt] = *(const long*)(tA + nl*272 + kt*32 + kq*8);
      afB[kt] = *(const long*)(tB + nl*272 + kt*32 + kq*8);
    }

    f32x4 acc[4][2];
#pragma unroll
    for (int g = 0; g < 4; ++g)
#pragma unroll
      for (int q = 0; q < 2; ++q) acc[g][q] = (f32x4){0.f,0.f,0.f,0.f};

    // ---- MFMA group A ----
    __builtin_amdgcn_s_setprio(1);
#pragma unroll
    for (int kt = 0; kt < 8; ++kt)
#pragma unroll
      for (int g = 0; g < 4; ++g)
#pragma unroll
        for (int q = 0; q < 2; ++q)
          acc[g][q] = __builtin_amdgcn_mfma_f32_16x16x32_fp8_fp8(afA[kt], wB[g][q][kt], acc[g][q], 0,0,0);
    __builtin_amdgcn_s_setprio(0);

    if (kq == 0){
#pragma unroll
      for (int g = 0; g < 4; ++g)
#pragma unroll
        for (int q = 0; q < 2; ++q)
          *(f32x4*)&xchA[w][g][q][nl][0] = acc[g][q];
    }

    // ---- MFMA group B (reuses acc regs; overlaps combine-A below via pipe async) ----
#pragma unroll
    for (int g = 0; g < 4; ++g)
#pragma unroll
      for (int q = 0; q < 2; ++q) acc[g][q] = (f32x4){0.f,0.f,0.f,0.f};
    __builtin_amdgcn_s_setprio(1);
#pragma unroll
    for (int kt = 0; kt < 8; ++kt)
#pragma unroll
      for (int g = 0; g < 4; ++g)
#pragma unroll
        for (int q = 0; q < 2; ++q)
          acc[g][q] = __builtin_amdgcn_mfma_f32_16x16x32_fp8_fp8(afB[kt], wB[g][q][kt], acc[g][q], 0,0,0);
    __builtin_amdgcn_s_setprio(0);

    asm volatile("s_waitcnt lgkmcnt(0)" ::: "memory");

    // ---- combine group A: cols c0, c0+1, batch kq ----
    {
      const int wslot = dir ? t : (s + 1);
      float h0, h1;
      {
        float i_ = xchA[w][0][q0][nx0][kq]*ISC + bf2f(gxcA[0][0]);
        float f_ = xchA[w][1][q0][nx0][kq]*ISC + bf2f(gxcA[1][0]);
        float g_ = xchA[w][2][q0][nx0][kq]*ISC + bf2f(gxcA[2][0]);
        float o_ = xchA[w][3][q0][nx0][kq]*ISC + bf2f(gxcA[3][0]);
        float cn = sigm(f_)*cA[0] + sigm(i_)*ftanh(g_);
        cA[0] = cn; h0 = sigm(o_)*ftanh(cn);
      }
      {
        float i_ = xchA[w][0][q0][nx1][kq]*ISC + bf2f(gxcA[0][1]);
        float f_ = xchA[w][1][q0][nx1][kq]*ISC + bf2f(gxcA[1][1]);
        float g_ = xchA[w][2][q0][nx1][kq]*ISC + bf2f(gxcA[2][1]);
        float o_ = xchA[w][3][q0][nx1][kq]*ISC + bf2f(gxcA[3][1]);
        float cn = sigm(f_)*cA[1] + sigm(i_)*ftanh(g_);
        cA[1] = cn; h1 = sigm(o_)*ftanh(cn);
      }
      unsigned hv;
      asm volatile("v_cvt_pk_bf16_f32 %0, %1, %2" : "=v"(hv) : "v"(h0), "v"(h1));
      *(unsigned*)(hbuf + (size_t)(wslot*BB + bgA*4 + kq)*HH + c0) = hv;
      *(unsigned short*)&h8[0][(s + 1) & 1][kq][hbyte] = cvt2fp8(h0*HSC, h1*HSC);
    }

    // publish group-B gates
    if (kq == 0){
#pragma unroll
      for (int g = 0; g < 4; ++g)
#pragma unroll
        for (int q = 0; q < 2; ++q)
          *(f32x4*)&xchB[w][g][q][nl][0] = acc[g][q];
    }
    asm volatile("s_waitcnt lgkmcnt(0)" ::: "memory");

    // ---- combine group B ----
    {
      const int wslot = dir ? t : (s + 1);
      float h0, h1;
      {
        float i_ = xchB[w][0][q0][nx0][kq]*ISC + bf2f(gxcB[0][0]);
        float f_ = xchB[w][1][q0][nx0][kq]*ISC + bf2f(gxcB[1][0]);
        float g_ = xchB[w][2][q0][nx0][kq]*ISC + bf2f(gxcB[2][0]);
        float o_ = xchB[w][3][q0][nx0][kq]*ISC + bf2f(gxcB[3][0]);
        float cn = sigm(f_)*cB[0] + sigm(i_)*ftanh(g_);
        cB[0] = cn; h0 = sigm(o_)*ftanh(cn);
      }
      {
        float i_ = xchB[w][0][q0][nx1][kq]*ISC + bf2f(gxcB[0][1]);
        float f_ = xchB[w][1][q0][nx1][kq]*ISC + bf2f(gxcB[1][1]);
        float g_ = xchB[w][2][q0][nx1][kq]*ISC + bf2f(gxcB[2][1]);
        float o_ = xchB[w][3][q0][nx1][kq]*ISC + bf2f(gxcB[3][1]);
        float cn = sigm(f_)*cB[1] + sigm(i_)*ftanh(g_);
        cB[1] = cn; h1 = sigm(o_)*ftanh(cn);
      }
      unsigned hv;
      asm volatile("v_cvt_pk_bf16_f32 %0, %1, %2" : "=v"(hv) : "v"(h0), "v"(h1));
      *(unsigned*)(hbuf + (size_t)(wslot*BB + bgB*4 + kq)*HH + c0) = hv;
      *(unsigned short*)&h8[1][(s + 1) & 1][kq][hbyte] = cvt2fp8(h0*HSC, h1*HSC);
    }

#pragma unroll
    for (int g = 0; g < 4; ++g)
#pragma unroll
      for (int j = 0; j < 2; ++j){
        gxcA[g][j] = gxnA[g][j];
        gxcB[g][j] = gxnB[g][j];
      }

    // lgkm-only barrier: LDS h8 is the only cross-wave dependency
    asm volatile("s_waitcnt lgkmcnt(0)" ::: "memory");
    __builtin_amdgcn_s_barrier();
    asm volatile("" ::: "memory");
  }
}

// ---------------- FC via MFMA, LDS-staged A (coalesced h reads) ----------------
__global__ __launch_bounds__(256,1) void k_fc(
    const unsigned short* __restrict__ hf, const unsigned short* __restrict__ hb,
    const float* __restrict__ fcW, const float* __restrict__ fcb,
    float* __restrict__ logits)
{
  __shared__ unsigned short Bs[32][516];
  __shared__ unsigned short Ah[4][32][260];
  __shared__ float fcb_s[32];
  const int tid = threadIdx.x;
  for (int i = tid; i < 32*512; i += 256){
    int tg = i >> 9, k = i & 511;
    Bs[tg][k] = f2bf(fcW[tg*512 + k]);
  }
  if (tid < 32) fcb_s[tid] = fcb[tid];
  __syncthreads();

  const int lane = tid & 63, w = tid >> 6;
  const int nl = lane & 15, kq = lane >> 4;
  const int pbase = blockIdx.x * 128;

  f32x4 acc[2][2];
#pragma unroll
  for (int mt = 0; mt < 2; ++mt)
#pragma unroll
    for (int nt = 0; nt < 2; ++nt) acc[mt][nt] = (f32x4){0.f,0.f,0.f,0.f};

  for (int half = 0; half < 2; ++half){
    for (int rr = 0; rr < 32; ++rr){
      int p = pbase + w*32 + rr;
      int t = p >> 6, b = p & 63;
      const unsigned short* src = half ? (hb + (size_t)(t*BB + b)*HH)
                                       : (hf + (size_t)((t+1)*BB + b)*HH);
      *(uint2*)&Ah[w][rr][lane*4] = *(const uint2*)(src + lane*4);
    }
#pragma unroll
    for (int kt = 0; kt < 8; ++kt){
      int kl = kt*32 + kq*4;
      bf16x8 a[2];
#pragma unroll
      for (int mt = 0; mt < 2; ++mt){
        const unsigned short* ar = &Ah[w][mt*16 + nl][kl];
        short4v lo = *(const short4v*)ar;
        short4v hi = *(const short4v*)(ar + 16);
        bf16x8 f = {lo[0],lo[1],lo[2],lo[3],hi[0],hi[1],hi[2],hi[3]};
        a[mt] = f;
      }
#pragma unroll
      for (int nt = 0; nt < 2; ++nt){
        const unsigned short* br = &Bs[nt*16 + nl][half*256 + kl];
        short4v lo = *(const short4v*)br;
        short4v hi = *(const short4v*)(br + 16);
        bf16x8 bv = {lo[0],lo[1],lo[2],lo[3],hi[0],hi[1],hi[2],hi[3]};
        acc[0][nt] = __builtin_amdgcn_mfma_f32_16x16x32_bf16(a[0], bv, acc[0][nt], 0,0,0);
        acc[1][nt] = __builtin_amdgcn_mfma_f32_16x16x32_bf16(a[1], bv, acc[1][nt], 0,0,0);
      }
    }
  }
#pragma unroll
  for (int mt = 0; mt < 2; ++mt)
#pragma unroll
    for (int nt = 0; nt < 2; ++nt)
#pragma unroll
      for (int r = 0; r < 4; ++r){
        int p = pbase + w*32 + mt*16 + kq*4 + r;
        int tg = nt*16 + nl;
        logits[(size_t)p*TT + tg] = acc[mt][nt][r] + fcb_s[tg];
      }
}

// ---------------- merged CRF: blocks 0-15 den, 16-31 vit (LDS hist), 32-47 num ----------------
__global__ void k_crf(const float* __restrict__ logits, const int* __restrict__ mask,
                      const int* __restrict__ labels,
                      const float* __restrict__ start, const float* __restrict__ endt,
                      const float* __restrict__ trans,
                      float* __restrict__ den, float* __restrict__ num,
                      float* __restrict__ preds)
{
  __shared__ float tr[1024];
  __shared__ unsigned char vh_l[4][SS-1][32];
  const int tid = threadIdx.x;
  const int role = blockIdx.x >> 4;
  const int bq   = blockIdx.x & 15;
  if (role != 2){
    for (int i = tid; i < 1024; i += 256) tr[i] = trans[i];
    __syncthreads();
  }
  const int lane = tid & 63, w = tid >> 6;
  const int b = bq*4 + w;
  const int grp = lane >> 5, tp = lane & 31;

  if (role == 0){
    float score = start[tp] + logits[(size_t)b*TT + tp];
    float em_c = logits[(size_t)(BB + b)*TT + tp];
    int   mk_c = mask[b*SS + 1];
    for (int s = 1; s < SS; ++s){
      int sn = (s + 1 < SS) ? s + 1 : s;
      float em_n = logits[(size_t)(sn*BB + b)*TT + tp];
      int   mk_n = mask[b*SS + sn];
      float m = -1e30f;
#pragma unroll
      for (int jj = 0; jj < 16; ++jj){
        int j = grp*16 + jj;
        float v = __shfl(score, j) + tr[j*32 + tp];
        m = fmaxf(m, v);
      }
      m = fmaxf(m, __shfl_xor(m, 32));
      float ssum = 0.f;
#pragma unroll
      for (int jj = 0; jj < 16; ++jj){
        int j = grp*16 + jj;
        float v = __shfl(score, j) + tr[j*32 + tp];
        ssum += __expf(v - m);
      }
      ssum += __shfl_xor(ssum, 32);
      float ns = m + __logf(ssum) + em_c;
      score = mk_c ? ns : score;
      em_c = em_n; mk_c = mk_n;
    }
    float v = score + endt[tp];
    float mm = v;
    for (int d = 1; d < 32; d <<= 1) mm = fmaxf(mm, __shfl_xor(mm, d));
    float se = __expf(v - mm);
    for (int d = 1; d < 32; d <<= 1) se += __shfl_xor(se, d);
    if (lane == 0) den[b] = mm + __logf(se);
  } else if (role == 1){
    float score = start[tp] + logits[(size_t)b*TT + tp];
    float em_c = logits[(size_t)(BB + b)*TT + tp];
    int   mk_c = mask[b*SS + 1];
    for (int s = 1; s < SS; ++s){
      int sn = (s + 1 < SS) ? s + 1 : s;
      float em_n = logits[(size_t)(sn*BB + b)*TT + tp];
      int   mk_n = mask[b*SS + sn];
      float m = -1e30f; int am = 0;
#pragma unroll
      for (int jj = 0; jj < 16; ++jj){
        int j = grp*16 + jj;
        float v = __shfl(score, j) + tr[j*32 + tp];
        if (v > m){ m = v; am = j; }
      }
      float om = __shfl_xor(m, 32); int oam = __shfl_xor(am, 32);
      if (om > m || (om == m && oam < am)){ m = om; am = oam; }
      float ns = m + em_c;
      int idx = mk_c ? am : tp;
      if (grp == 0) vh_l[w][s-1][tp] = (unsigned char)idx;
      score = mk_c ? ns : score;
      em_c = em_n; mk_c = mk_n;
    }
    float v = score + endt[tp]; int a = tp;
    for (int d = 1; d < 32; d <<= 1){
      float ov = __shfl_xor(v, d); int oa = __shfl_xor(a, d);
      if (ov > v || (ov == v && oa < a)){ v = ov; a = oa; }
    }
    int tag = __shfl(a, 0);
    if (lane == 0) preds[(size_t)b*SS + SS - 1] = (float)tag;
    for (int s = SS - 1; s >= 1; --s){
      int rv = vh_l[w][s-1][tp];
      int pv = __shfl(rv, tag);
      if (lane == 0) preds[(size_t)b*SS + s - 1] = (float)pv;
      tag = pv;
    }
  } else {
    float acc = 0.f; int mcnt = 0;
    for (int s = lane; s < SS; s += 64){
      int mk = mask[b*SS + s];
      mcnt += mk;
      if (s >= 1){
        int tg = labels[b*SS + s], tpp = labels[b*SS + s - 1];
        float v = trans[tpp*32 + tg] + logits[(size_t)(s*BB + b)*TT + tg];
        acc += mk ? v : 0.f;
      }
    }
    for (int d = 1; d < 64; d <<= 1){ acc += __shfl_xor(acc, d); mcnt += __shfl_xor(mcnt, d); }
    if (lane == 0){
      int t0 = labels[b*SS];
      int tl = labels[b*SS + (mcnt - 1)];
      num[b] = start[t0] + logits[(size_t)b*TT + t0] + acc + endt[tl];
    }
  }
}

// ---------------- loss ----------------
__global__ void k_loss(const float* __restrict__ num, const float* __restrict__ den,
                       float* __restrict__ out)
{
  int l = threadIdx.x;
  float v = num[l] - den[l];
  for (int d = 1; d < 64; d <<= 1) v += __shfl_xor(v, d);
  if (l == 0) out[BB*SS] = -v;
}

extern "C" void kernel_launch(void* const* d_in, const int* in_sizes, int n_in,
                              void* d_out, int out_size, void* d_ws, size_t ws_size,
                              hipStream_t stream)
{
  const int*   seq       = (const int*)  d_in[0];
  const int*   mask      = (const int*)  d_in[1];
  const int*   labels    = (const int*)  d_in[2];
  const float* embedding = (const float*)d_in[3];
  const float* Wih_f     = (const float*)d_in[4];
  const float* Whh_f     = (const float*)d_in[5];
  const float* bih_f     = (const float*)d_in[6];
  const float* bhh_f     = (const float*)d_in[7];
  const float* Wih_b     = (const float*)d_in[8];
  const float* Whh_b     = (const float*)d_in[9];
  const float* bih_b     = (const float*)d_in[10];
  const float* bhh_b     = (const float*)d_in[11];
  const float* fcW       = (const float*)d_in[12];
  const float* fcb       = (const float*)d_in[13];
  const float* start_t   = (const float*)d_in[14];
  const float* end_t     = (const float*)d_in[15];
  const float* trans     = (const float*)d_in[16];

  char* ws = (char*)d_ws;
  size_t off = 0;
  unsigned short* gxb = (unsigned short*)(ws + off); off += (size_t)2*SS*1024*64*2;     // 128 MiB
  unsigned short* hf  = (unsigned short*)(ws + off); off += (size_t)(SS+1)*BB*HH*2;     // 16 MiB
  unsigned short* hb  = (unsigned short*)(ws + off); off += (size_t)(SS+1)*BB*HH*2;     // 16 MiB
  float*          lgt = (float*)(ws + off);          off += (size_t)SS*BB*TT*4;         // 4 MiB
  float*          den = (float*)(ws + off);          off += 256;
  float*          num = (float*)(ws + off);          off += 256;

  hipMemsetAsync(hf, 0, (size_t)BB*HH*2, stream);
  hipMemsetAsync(hb + (size_t)SS*BB*HH, 0, (size_t)BB*HH*2, stream);

  k_xgemm<<<dim3(256,2), 256, 0, stream>>>(seq, embedding, Wih_f, Wih_b,
                                           bih_f, bhh_f, bih_b, bhh_b, gxb);
  k_lstm<<<16, 512, 0, stream>>>(gxb, Whh_f, Whh_b, hf, hb);
  k_fc<<<256, 256, 0, stream>>>(hf, hb, fcW, fcb, lgt);
  k_crf<<<48, 256, 0, stream>>>(lgt, mask, labels, start_t, end_t, trans, den, num, (float*)d_out);
  k_loss<<<1, 64, 0, stream>>>(num, den, (float*)d_out);
}

// Round 12
// 1456.966 us; speedup vs baseline: 1.8475x; 1.8475x over previous
//
#include <hip/hip_runtime.h>
#include <stdint.h>

#define SS 512
#define BB 64
#define HH 256
#define TT 32

typedef __attribute__((ext_vector_type(8))) short bf16x8;
typedef __attribute__((ext_vector_type(4))) short short4v;
typedef __attribute__((ext_vector_type(4))) float f32x4;

__device__ __forceinline__ unsigned short f2bf(float f){
  unsigned u = __float_as_uint(f);
  unsigned r = (u + 0x7FFFu + ((u >> 16) & 1u)) >> 16;
  return (unsigned short)r;
}
__device__ __forceinline__ float bf2f(unsigned short s){
  return __uint_as_float(((unsigned)s) << 16);
}
__device__ __forceinline__ float sigm(float x){ return 1.0f/(1.0f+__expf(-x)); }
__device__ __forceinline__ float ftanh(float x){
  float e = __expf(2.f*x);
  return 1.f - 2.f/(e + 1.f);
}
__device__ __forceinline__ unsigned cvt4fp8(float a0, float a1, float a2, float a3){
  int d = __builtin_amdgcn_cvt_pk_fp8_f32(a0, a1, 0, false);
  d = __builtin_amdgcn_cvt_pk_fp8_f32(a2, a3, d, true);
  return (unsigned)d;
}
__device__ __forceinline__ unsigned char cvt1fp8(float a){
  int d = __builtin_amdgcn_cvt_pk_fp8_f32(a, a, 0, false);
  return (unsigned char)(d & 0xFF);
}

// swizzled-LDS fragment read (used by k_xgemm only)
__device__ __forceinline__ bf16x8 afrag(const unsigned short* A, int mt, int ktp, int nl, int kq){
  int m = mt*16 + nl;
  int sw = (m & 7) << 3;
  int kk = ktp*32 + kq*4;
  short4v lo = *(const short4v*)(A + (m << 8) + (kk ^ sw));
  short4v hi = *(const short4v*)(A + (m << 8) + ((kk + 16) ^ sw));
  bf16x8 r = {lo[0],lo[1],lo[2],lo[3],hi[0],hi[1],hi[2],hi[3]};
  return r;
}

// ---------------- fused gather + x@Wih^T GEMM (+bias fold) -> gx bf16 [dir*16+bg][t][col][b4] ----------------
__global__ __launch_bounds__(256,1) void k_xgemm(
    const int* __restrict__ seq, const float* __restrict__ emb,
    const float* __restrict__ Wih_f, const float* __restrict__ Wih_b,
    const float* __restrict__ bih_f, const float* __restrict__ bhh_f,
    const float* __restrict__ bih_b, const float* __restrict__ bhh_b,
    unsigned short* __restrict__ gx)
{
  __shared__ __align__(16) unsigned short A_l[128*256];  // 64 KiB
  __shared__ __align__(16) unsigned short B_l[64*256];   // 32 KiB

  const int tid = threadIdx.x;
  const int lane = tid & 63, w = tid >> 6;
  const int nl = lane & 15, kq = lane >> 4;
  const int pbase = blockIdx.x * 128;
  const int dir = blockIdx.y;
  const float* Wih  = dir ? Wih_b : Wih_f;
  const float* bihd = dir ? bih_b : bih_f;
  const float* bhhd = dir ? bhh_b : bhh_f;

#pragma unroll
  for (int i = 0; i < 16; ++i){
    int c = tid + i*256;
    int m = c >> 5, k8 = c & 31;
    int p = pbase + m, t = p >> 6, b = p & 63;
    int er = seq[b*SS + t];
    const float* s = emb + (size_t)er*HH + k8*8;
    float4 x0 = *(const float4*)s, x1 = *(const float4*)(s+4);
    union { unsigned short u[8]; uint4 v; } o;
    o.u[0]=f2bf(x0.x); o.u[1]=f2bf(x0.y); o.u[2]=f2bf(x0.z); o.u[3]=f2bf(x0.w);
    o.u[4]=f2bf(x1.x); o.u[5]=f2bf(x1.y); o.u[6]=f2bf(x1.z); o.u[7]=f2bf(x1.w);
    *(uint4*)&A_l[(m << 8) + ((k8*8) ^ ((m & 7) << 3))] = o.v;
  }

  for (int nb = 0; nb < 16; ++nb){
    __syncthreads();
#pragma unroll
    for (int i = 0; i < 8; ++i){
      int c = tid + i*256;
      int m = c >> 5, k8 = c & 31;
      const float* s = Wih + (size_t)(nb*64 + m)*HH + k8*8;
      float4 x0 = *(const float4*)s, x1 = *(const float4*)(s+4);
      union { unsigned short u[8]; uint4 v; } o;
      o.u[0]=f2bf(x0.x); o.u[1]=f2bf(x0.y); o.u[2]=f2bf(x0.z); o.u[3]=f2bf(x0.w);
      o.u[4]=f2bf(x1.x); o.u[5]=f2bf(x1.y); o.u[6]=f2bf(x1.z); o.u[7]=f2bf(x1.w);
      *(uint4*)&B_l[(m << 8) + ((k8*8) ^ ((m & 7) << 3))] = o.v;
    }
    __syncthreads();

    f32x4 acc[2][4];
#pragma unroll
    for (int mt = 0; mt < 2; ++mt)
#pragma unroll
      for (int nt = 0; nt < 4; ++nt) acc[mt][nt] = (f32x4){0.f,0.f,0.f,0.f};

#pragma unroll
    for (int kt = 0; kt < 8; ++kt){
      bf16x8 a0 = afrag(A_l, w*2+0, kt, nl, kq);
      bf16x8 a1 = afrag(A_l, w*2+1, kt, nl, kq);
#pragma unroll
      for (int nt = 0; nt < 4; ++nt){
        bf16x8 bv = afrag(B_l, nt, kt, nl, kq);
        acc[0][nt] = __builtin_amdgcn_mfma_f32_16x16x32_bf16(a0, bv, acc[0][nt], 0,0,0);
        acc[1][nt] = __builtin_amdgcn_mfma_f32_16x16x32_bf16(a1, bv, acc[1][nt], 0,0,0);
      }
    }

#pragma unroll
    for (int mt = 0; mt < 2; ++mt)
#pragma unroll
      for (int nt = 0; nt < 4; ++nt){
        int p0 = pbase + w*32 + mt*16 + kq*4;
        int t = p0 >> 6, b0 = p0 & 63;
        int col = nb*64 + nt*16 + nl;
        float bs = bihd[col] + bhhd[col];      // bias folded into gx
        union { unsigned short u[4]; uint2 v; } o;
        o.u[0]=f2bf(acc[mt][nt][0] + bs); o.u[1]=f2bf(acc[mt][nt][1] + bs);
        o.u[2]=f2bf(acc[mt][nt][2] + bs); o.u[3]=f2bf(acc[mt][nt][3] + bs);
        *(uint2*)(gx + ((size_t)(dir*16 + (b0 >> 2))*SS + t)*4096 + col*4) = o.v;
      }
  }
}

// ---------------- LSTM: 32 blocks x 1024 threads (16 waves = 4/SIMD for latency hiding) ----------------
// Block: dir = blk>>4, bg = blk&15 -> batch rows bg*4..+3.
// Wave w (0..15): all 4 gates for cols w*16..+15 -> wB = 64 VGPR/lane (fits 128 cap, no spill).
// One lgkm-only barrier per step; combine = 1 h-value per lane (batch kq, col w*16+nl).
#define WSC 64.0f
#define HSC 16.0f
#define ISC (1.0f/(WSC*HSC))

__global__ __launch_bounds__(1024,1) void k_lstm(
    const unsigned short* __restrict__ gx,
    const float* __restrict__ Whh_f, const float* __restrict__ Whh_b,
    unsigned short* __restrict__ hf, unsigned short* __restrict__ hb)
{
  __shared__ __align__(16) unsigned char h8[2][16][272];   // fp8 A-tile, double-buffered (8.5 KB)
  __shared__ __align__(16) float xch[16][4][16][4];        // per-wave gate bounce (16 KB)

  const int tid  = threadIdx.x;
  const int lane = tid & 63;
  const int w    = tid >> 6;           // 0..15
  const int nl   = lane & 15;
  const int kq   = lane >> 4;          // MFMA k-quarter; in combine = batch row
  const int dir  = blockIdx.x >> 4;
  const int bg   = blockIdx.x & 15;

  const float* Whh = dir ? Whh_b : Whh_f;
  unsigned short* hbuf = dir ? hb : hf;
  const unsigned short* gxd = gx + (size_t)(dir*16 + bg)*SS*4096;

  // Whh -> fp8 B-fragments in regs: wB[gate][kt] (64 VGPR/lane)
  long wB[4][8];
#pragma unroll
  for (int g = 0; g < 4; ++g)
#pragma unroll
    for (int kt = 0; kt < 8; ++kt){
      int ncol = g*256 + w*16 + nl;
      const float* p = Whh + (size_t)ncol*HH + kt*32 + kq*4;
      float4 lo = *(const float4*)p;
      float4 hi = *(const float4*)(p + 16);
      union { unsigned d[2]; long l; } u;
      u.d[0] = cvt4fp8(lo.x*WSC, lo.y*WSC, lo.z*WSC, lo.w*WSC);
      u.d[1] = cvt4fp8(hi.x*WSC, hi.y*WSC, hi.z*WSC, hi.w*WSC);
      wB[g][kt] = u.l;
    }

  // combine mapping: batch kq, col cc = w*16 + nl
  const int cc = w*16 + nl;
  const int hbyte = (cc >> 5)*32 + ((cc & 15) >> 2)*8 + ((cc & 16) ? 4 : 0) + (cc & 3);

  for (int i = tid; i < 2176; i += 1024) ((unsigned*)h8)[i] = 0;
  __syncthreads();

  float c0 = 0.f;

  unsigned short gxc[4], gxn[4];
  {
    const int t0 = dir ? (SS-1) : 0;
    const unsigned short* gp = gxd + (size_t)t0*4096;
#pragma unroll
    for (int g = 0; g < 4; ++g)
      gxc[g] = gp[(g*256 + cc)*4 + kq];
  }

  for (int s = 0; s < SS; ++s){
    const int t = dir ? (SS-1-s) : s;

    // prefetch next-step gx (retires under MFMA)
    {
      int sn = s + 1;
      int tn = (sn < SS) ? (dir ? (SS-1-sn) : sn) : t;
      const unsigned short* gp = gxd + (size_t)tn*4096;
#pragma unroll
      for (int g = 0; g < 4; ++g)
        gxn[g] = gp[(g*256 + cc)*4 + kq];
    }

    // A-fragments: 8 x ds_read_b64 (rows 4..15 are constant zeros)
    const unsigned char* tp8 = &h8[s & 1][0][0];
    long af[8];
#pragma unroll
    for (int kt = 0; kt < 8; ++kt)
      af[kt] = *(const long*)(tp8 + nl*272 + kt*32 + kq*8);

    f32x4 acc[4];
#pragma unroll
    for (int g = 0; g < 4; ++g) acc[g] = (f32x4){0.f,0.f,0.f,0.f};

#pragma unroll
    for (int kt = 0; kt < 8; ++kt)
#pragma unroll
      for (int g = 0; g < 4; ++g)
        acc[g] = __builtin_amdgcn_mfma_f32_16x16x32_fp8_fp8(af[kt], wB[g][kt], acc[g], 0,0,0);

    // intra-wave gate exchange: lanes with kq==0 hold batch rows 0-3 in regs 0-3
    if (kq == 0){
#pragma unroll
      for (int g = 0; g < 4; ++g)
        *(f32x4*)&xch[w][g][nl][0] = acc[g];     // ds_write_b128, conflict-free
    }
    asm volatile("s_waitcnt lgkmcnt(0)" ::: "memory");

    // combine: lane (batch kq, col cc) -> ONE h value
    {
      const int wslot = dir ? t : (s + 1);
      float i_ = xch[w][0][nl][kq]*ISC + bf2f(gxc[0]);
      float f_ = xch[w][1][nl][kq]*ISC + bf2f(gxc[1]);
      float g_ = xch[w][2][nl][kq]*ISC + bf2f(gxc[2]);
      float o_ = xch[w][3][nl][kq]*ISC + bf2f(gxc[3]);
      float cn = sigm(f_)*c0 + sigm(i_)*ftanh(g_);
      c0 = cn;
      float h = sigm(o_)*ftanh(cn);
      hbuf[(size_t)(wslot*BB + bg*4 + kq)*HH + cc] = f2bf(h);   // global store, not drained in-loop
      h8[(s + 1) & 1][kq][hbyte] = cvt1fp8(h*HSC);              // fp8 into next A-tile
    }

#pragma unroll
    for (int g = 0; g < 4; ++g) gxc[g] = gxn[g];

    // lgkm-only barrier: LDS h8 is the only cross-wave dependency
    asm volatile("s_waitcnt lgkmcnt(0)" ::: "memory");
    __builtin_amdgcn_s_barrier();
    asm volatile("" ::: "memory");
  }
}

// ---------------- FC via MFMA, LDS-staged A (coalesced h reads) ----------------
__global__ __launch_bounds__(256,1) void k_fc(
    const unsigned short* __restrict__ hf, const unsigned short* __restrict__ hb,
    const float* __restrict__ fcW, const float* __restrict__ fcb,
    float* __restrict__ logits)
{
  __shared__ unsigned short Bs[32][516];
  __shared__ unsigned short Ah[4][32][260];
  __shared__ float fcb_s[32];
  const int tid = threadIdx.x;
  for (int i = tid; i < 32*512; i += 256){
    int tg = i >> 9, k = i & 511;
    Bs[tg][k] = f2bf(fcW[tg*512 + k]);
  }
  if (tid < 32) fcb_s[tid] = fcb[tid];
  __syncthreads();

  const int lane = tid & 63, w = tid >> 6;
  const int nl = lane & 15, kq = lane >> 4;
  const int pbase = blockIdx.x * 128;

  f32x4 acc[2][2];
#pragma unroll
  for (int mt = 0; mt < 2; ++mt)
#pragma unroll
    for (int nt = 0; nt < 2; ++nt) acc[mt][nt] = (f32x4){0.f,0.f,0.f,0.f};

  for (int half = 0; half < 2; ++half){
    for (int rr = 0; rr < 32; ++rr){
      int p = pbase + w*32 + rr;
      int t = p >> 6, b = p & 63;
      const unsigned short* src = half ? (hb + (size_t)(t*BB + b)*HH)
                                       : (hf + (size_t)((t+1)*BB + b)*HH);
      *(uint2*)&Ah[w][rr][lane*4] = *(const uint2*)(src + lane*4);
    }
#pragma unroll
    for (int kt = 0; kt < 8; ++kt){
      int kl = kt*32 + kq*4;
      bf16x8 a[2];
#pragma unroll
      for (int mt = 0; mt < 2; ++mt){
        const unsigned short* ar = &Ah[w][mt*16 + nl][kl];
        short4v lo = *(const short4v*)ar;
        short4v hi = *(const short4v*)(ar + 16);
        bf16x8 f = {lo[0],lo[1],lo[2],lo[3],hi[0],hi[1],hi[2],hi[3]};
        a[mt] = f;
      }
#pragma unroll
      for (int nt = 0; nt < 2; ++nt){
        const unsigned short* br = &Bs[nt*16 + nl][half*256 + kl];
        short4v lo = *(const short4v*)br;
        short4v hi = *(const short4v*)(br + 16);
        bf16x8 bv = {lo[0],lo[1],lo[2],lo[3],hi[0],hi[1],hi[2],hi[3]};
        acc[0][nt] = __builtin_amdgcn_mfma_f32_16x16x32_bf16(a[0], bv, acc[0][nt], 0,0,0);
        acc[1][nt] = __builtin_amdgcn_mfma_f32_16x16x32_bf16(a[1], bv, acc[1][nt], 0,0,0);
      }
    }
  }
#pragma unroll
  for (int mt = 0; mt < 2; ++mt)
#pragma unroll
    for (int nt = 0; nt < 2; ++nt)
#pragma unroll
      for (int r = 0; r < 4; ++r){
        int p = pbase + w*32 + mt*16 + kq*4 + r;
        int tg = nt*16 + nl;
        logits[(size_t)p*TT + tg] = acc[mt][nt][r] + fcb_s[tg];
      }
}

// ---------------- merged CRF: blocks 0-15 den, 16-31 vit (LDS hist), 32-47 num ----------------
__global__ void k_crf(const float* __restrict__ logits, const int* __restrict__ mask,
                      const int* __restrict__ labels,
                      const float* __restrict__ start, const float* __restrict__ endt,
                      const float* __restrict__ trans,
                      float* __restrict__ den, float* __restrict__ num,
                      float* __restrict__ preds)
{
  __shared__ float tr[1024];
  __shared__ unsigned char vh_l[4][SS-1][32];
  const int tid = threadIdx.x;
  const int role = blockIdx.x >> 4;
  const int bq   = blockIdx.x & 15;
  if (role != 2){
    for (int i = tid; i < 1024; i += 256) tr[i] = trans[i];
    __syncthreads();
  }
  const int lane = tid & 63, w = tid >> 6;
  const int b = bq*4 + w;
  const int grp = lane >> 5, tp = lane & 31;

  if (role == 0){
    float score = start[tp] + logits[(size_t)b*TT + tp];
    float em_c = logits[(size_t)(BB + b)*TT + tp];
    int   mk_c = mask[b*SS + 1];
    for (int s = 1; s < SS; ++s){
      int sn = (s + 1 < SS) ? s + 1 : s;
      float em_n = logits[(size_t)(sn*BB + b)*TT + tp];
      int   mk_n = mask[b*SS + sn];
      float m = -1e30f;
#pragma unroll
      for (int jj = 0; jj < 16; ++jj){
        int j = grp*16 + jj;
        float v = __shfl(score, j) + tr[j*32 + tp];
        m = fmaxf(m, v);
      }
      m = fmaxf(m, __shfl_xor(m, 32));
      float ssum = 0.f;
#pragma unroll
      for (int jj = 0; jj < 16; ++jj){
        int j = grp*16 + jj;
        float v = __shfl(score, j) + tr[j*32 + tp];
        ssum += __expf(v - m);
      }
      ssum += __shfl_xor(ssum, 32);
      float ns = m + __logf(ssum) + em_c;
      score = mk_c ? ns : score;
      em_c = em_n; mk_c = mk_n;
    }
    float v = score + endt[tp];
    float mm = v;
    for (int d = 1; d < 32; d <<= 1) mm = fmaxf(mm, __shfl_xor(mm, d));
    float se = __expf(v - mm);
    for (int d = 1; d < 32; d <<= 1) se += __shfl_xor(se, d);
    if (lane == 0) den[b] = mm + __logf(se);
  } else if (role == 1){
    float score = start[tp] + logits[(size_t)b*TT + tp];
    float em_c = logits[(size_t)(BB + b)*TT + tp];
    int   mk_c = mask[b*SS + 1];
    for (int s = 1; s < SS; ++s){
      int sn = (s + 1 < SS) ? s + 1 : s;
      float em_n = logits[(size_t)(sn*BB + b)*TT + tp];
      int   mk_n = mask[b*SS + sn];
      float m = -1e30f; int am = 0;
#pragma unroll
      for (int jj = 0; jj < 16; ++jj){
        int j = grp*16 + jj;
        float v = __shfl(score, j) + tr[j*32 + tp];
        if (v > m){ m = v; am = j; }
      }
      float om = __shfl_xor(m, 32); int oam = __shfl_xor(am, 32);
      if (om > m || (om == m && oam < am)){ m = om; am = oam; }
      float ns = m + em_c;
      int idx = mk_c ? am : tp;
      if (grp == 0) vh_l[w][s-1][tp] = (unsigned char)idx;
      score = mk_c ? ns : score;
      em_c = em_n; mk_c = mk_n;
    }
    float v = score + endt[tp]; int a = tp;
    for (int d = 1; d < 32; d <<= 1){
      float ov = __shfl_xor(v, d); int oa = __shfl_xor(a, d);
      if (ov > v || (ov == v && oa < a)){ v = ov; a = oa; }
    }
    int tag = __shfl(a, 0);
    if (lane == 0) preds[(size_t)b*SS + SS - 1] = (float)tag;
    for (int s = SS - 1; s >= 1; --s){
      int rv = vh_l[w][s-1][tp];
      int pv = __shfl(rv, tag);
      if (lane == 0) preds[(size_t)b*SS + s - 1] = (float)pv;
      tag = pv;
    }
  } else {
    float acc = 0.f; int mcnt = 0;
    for (int s = lane; s < SS; s += 64){
      int mk = mask[b*SS + s];
      mcnt += mk;
      if (s >= 1){
        int tg = labels[b*SS + s], tpp = labels[b*SS + s - 1];
        float v = trans[tpp*32 + tg] + logits[(size_t)(s*BB + b)*TT + tg];
        acc += mk ? v : 0.f;
      }
    }
    for (int d = 1; d < 64; d <<= 1){ acc += __shfl_xor(acc, d); mcnt += __shfl_xor(mcnt, d); }
    if (lane == 0){
      int t0 = labels[b*SS];
      int tl = labels[b*SS + (mcnt - 1)];
      num[b] = start[t0] + logits[(size_t)b*TT + t0] + acc + endt[tl];
    }
  }
}

// ---------------- loss ----------------
__global__ void k_loss(const float* __restrict__ num, const float* __restrict__ den,
                       float* __restrict__ out)
{
  int l = threadIdx.x;
  float v = num[l] - den[l];
  for (int d = 1; d < 64; d <<= 1) v += __shfl_xor(v, d);
  if (l == 0) out[BB*SS] = -v;
}

extern "C" void kernel_launch(void* const* d_in, const int* in_sizes, int n_in,
                              void* d_out, int out_size, void* d_ws, size_t ws_size,
                              hipStream_t stream)
{
  const int*   seq       = (const int*)  d_in[0];
  const int*   mask      = (const int*)  d_in[1];
  const int*   labels    = (const int*)  d_in[2];
  const float* embedding = (const float*)d_in[3];
  const float* Wih_f     = (const float*)d_in[4];
  const float* Whh_f     = (const float*)d_in[5];
  const float* bih_f     = (const float*)d_in[6];
  const float* bhh_f     = (const float*)d_in[7];
  const float* Wih_b     = (const float*)d_in[8];
  const float* Whh_b     = (const float*)d_in[9];
  const float* bih_b     = (const float*)d_in[10];
  const float* bhh_b     = (const float*)d_in[11];
  const float* fcW       = (const float*)d_in[12];
  const float* fcb       = (const float*)d_in[13];
  const float* start_t   = (const float*)d_in[14];
  const float* end_t     = (const float*)d_in[15];
  const float* trans     = (const float*)d_in[16];

  char* ws = (char*)d_ws;
  size_t off = 0;
  unsigned short* gxb = (unsigned short*)(ws + off); off += (size_t)2*SS*1024*64*2;     // 128 MiB
  unsigned short* hf  = (unsigned short*)(ws + off); off += (size_t)(SS+1)*BB*HH*2;     // 16 MiB
  unsigned short* hb  = (unsigned short*)(ws + off); off += (size_t)(SS+1)*BB*HH*2;     // 16 MiB
  float*          lgt = (float*)(ws + off);          off += (size_t)SS*BB*TT*4;         // 4 MiB
  float*          den = (float*)(ws + off);          off += 256;
  float*          num = (float*)(ws + off);          off += 256;

  k_xgemm<<<dim3(256,2), 256, 0, stream>>>(seq, embedding, Wih_f, Wih_b,
                                           bih_f, bhh_f, bih_b, bhh_b, gxb);
  k_lstm<<<32, 1024, 0, stream>>>(gxb, Whh_f, Whh_b, hf, hb);
  k_fc<<<256, 256, 0, stream>>>(hf, hb, fcW, fcb, lgt);
  k_crf<<<48, 256, 0, stream>>>(lgt, mask, labels, start_t, end_t, trans, den, num, (float*)d_out);
  k_loss<<<1, 64, 0, stream>>>(num, den, (float*)d_out);
}

// Round 13
// 1441.266 us; speedup vs baseline: 1.8677x; 1.0109x over previous
//
#include <hip/hip_runtime.h>
#include <stdint.h>

#define SS 512
#define BB 64
#define HH 256
#define TT 32

typedef __attribute__((ext_vector_type(8))) short bf16x8;
typedef __attribute__((ext_vector_type(4))) short short4v;
typedef __attribute__((ext_vector_type(4))) float f32x4;

__device__ __forceinline__ unsigned short f2bf(float f){
  unsigned u = __float_as_uint(f);
  unsigned r = (u + 0x7FFFu + ((u >> 16) & 1u)) >> 16;
  return (unsigned short)r;
}
__device__ __forceinline__ float bf2f(unsigned short s){
  return __uint_as_float(((unsigned)s) << 16);
}
__device__ __forceinline__ float sigm(float x){ return 1.0f/(1.0f+__expf(-x)); }
__device__ __forceinline__ float ftanh(float x){
  float e = __expf(2.f*x);
  return 1.f - 2.f/(e + 1.f);
}
__device__ __forceinline__ unsigned cvt4fp8(float a0, float a1, float a2, float a3){
  int d = __builtin_amdgcn_cvt_pk_fp8_f32(a0, a1, 0, false);
  d = __builtin_amdgcn_cvt_pk_fp8_f32(a2, a3, d, true);
  return (unsigned)d;
}
__device__ __forceinline__ unsigned char cvt1fp8(float a){
  int d = __builtin_amdgcn_cvt_pk_fp8_f32(a, a, 0, false);
  return (unsigned char)(d & 0xFF);
}

// swizzled-LDS fragment read (used by k_xgemm only)
__device__ __forceinline__ bf16x8 afrag(const unsigned short* A, int mt, int ktp, int nl, int kq){
  int m = mt*16 + nl;
  int sw = (m & 7) << 3;
  int kk = ktp*32 + kq*4;
  short4v lo = *(const short4v*)(A + (m << 8) + (kk ^ sw));
  short4v hi = *(const short4v*)(A + (m << 8) + ((kk + 16) ^ sw));
  bf16x8 r = {lo[0],lo[1],lo[2],lo[3],hi[0],hi[1],hi[2],hi[3]};
  return r;
}

// ---------------- fused gather + x@Wih^T GEMM (+bias fold) -> gx bf16 [dir*16+bg][t][col][b4] ----------------
__global__ __launch_bounds__(256,1) void k_xgemm(
    const int* __restrict__ seq, const float* __restrict__ emb,
    const float* __restrict__ Wih_f, const float* __restrict__ Wih_b,
    const float* __restrict__ bih_f, const float* __restrict__ bhh_f,
    const float* __restrict__ bih_b, const float* __restrict__ bhh_b,
    unsigned short* __restrict__ gx)
{
  __shared__ __align__(16) unsigned short A_l[128*256];  // 64 KiB
  __shared__ __align__(16) unsigned short B_l[64*256];   // 32 KiB

  const int tid = threadIdx.x;
  const int lane = tid & 63, w = tid >> 6;
  const int nl = lane & 15, kq = lane >> 4;
  const int pbase = blockIdx.x * 128;
  const int dir = blockIdx.y;
  const float* Wih  = dir ? Wih_b : Wih_f;
  const float* bihd = dir ? bih_b : bih_f;
  const float* bhhd = dir ? bhh_b : bhh_f;

#pragma unroll
  for (int i = 0; i < 16; ++i){
    int c = tid + i*256;
    int m = c >> 5, k8 = c & 31;
    int p = pbase + m, t = p >> 6, b = p & 63;
    int er = seq[b*SS + t];
    const float* s = emb + (size_t)er*HH + k8*8;
    float4 x0 = *(const float4*)s, x1 = *(const float4*)(s+4);
    union { unsigned short u[8]; uint4 v; } o;
    o.u[0]=f2bf(x0.x); o.u[1]=f2bf(x0.y); o.u[2]=f2bf(x0.z); o.u[3]=f2bf(x0.w);
    o.u[4]=f2bf(x1.x); o.u[5]=f2bf(x1.y); o.u[6]=f2bf(x1.z); o.u[7]=f2bf(x1.w);
    *(uint4*)&A_l[(m << 8) + ((k8*8) ^ ((m & 7) << 3))] = o.v;
  }

  for (int nb = 0; nb < 16; ++nb){
    __syncthreads();
#pragma unroll
    for (int i = 0; i < 8; ++i){
      int c = tid + i*256;
      int m = c >> 5, k8 = c & 31;
      const float* s = Wih + (size_t)(nb*64 + m)*HH + k8*8;
      float4 x0 = *(const float4*)s, x1 = *(const float4*)(s+4);
      union { unsigned short u[8]; uint4 v; } o;
      o.u[0]=f2bf(x0.x); o.u[1]=f2bf(x0.y); o.u[2]=f2bf(x0.z); o.u[3]=f2bf(x0.w);
      o.u[4]=f2bf(x1.x); o.u[5]=f2bf(x1.y); o.u[6]=f2bf(x1.z); o.u[7]=f2bf(x1.w);
      *(uint4*)&B_l[(m << 8) + ((k8*8) ^ ((m & 7) << 3))] = o.v;
    }
    __syncthreads();

    f32x4 acc[2][4];
#pragma unroll
    for (int mt = 0; mt < 2; ++mt)
#pragma unroll
      for (int nt = 0; nt < 4; ++nt) acc[mt][nt] = (f32x4){0.f,0.f,0.f,0.f};

#pragma unroll
    for (int kt = 0; kt < 8; ++kt){
      bf16x8 a0 = afrag(A_l, w*2+0, kt, nl, kq);
      bf16x8 a1 = afrag(A_l, w*2+1, kt, nl, kq);
#pragma unroll
      for (int nt = 0; nt < 4; ++nt){
        bf16x8 bv = afrag(B_l, nt, kt, nl, kq);
        acc[0][nt] = __builtin_amdgcn_mfma_f32_16x16x32_bf16(a0, bv, acc[0][nt], 0,0,0);
        acc[1][nt] = __builtin_amdgcn_mfma_f32_16x16x32_bf16(a1, bv, acc[1][nt], 0,0,0);
      }
    }

#pragma unroll
    for (int mt = 0; mt < 2; ++mt)
#pragma unroll
      for (int nt = 0; nt < 4; ++nt){
        int p0 = pbase + w*32 + mt*16 + kq*4;
        int t = p0 >> 6, b0 = p0 & 63;
        int col = nb*64 + nt*16 + nl;
        float bs = bihd[col] + bhhd[col];      // bias folded into gx
        union { unsigned short u[4]; uint2 v; } o;
        o.u[0]=f2bf(acc[mt][nt][0] + bs); o.u[1]=f2bf(acc[mt][nt][1] + bs);
        o.u[2]=f2bf(acc[mt][nt][2] + bs); o.u[3]=f2bf(acc[mt][nt][3] + bs);
        *(uint2*)(gx + ((size_t)(dir*16 + (b0 >> 2))*SS + t)*4096 + col*4) = o.v;
      }
  }
}

// ---------------- LSTM: 32 blocks x 1024 threads (16 waves = 4/SIMD for latency hiding) ----------------
// Block: dir = blk>>4, bg = blk&15 -> batch rows bg*4..+3.
// Wave w (0..15): all 4 gates for cols w*16..+15 -> wB = 64 VGPR/lane (fits 128 cap, no spill).
// One lgkm-only barrier per step; combine = 1 h-value per lane (batch kq, col w*16+nl).
#define WSC 64.0f
#define HSC 16.0f
#define ISC (1.0f/(WSC*HSC))

__global__ __launch_bounds__(1024,1) void k_lstm(
    const unsigned short* __restrict__ gx,
    const float* __restrict__ Whh_f, const float* __restrict__ Whh_b,
    unsigned short* __restrict__ hf, unsigned short* __restrict__ hb)
{
  __shared__ __align__(16) unsigned char h8[2][16][272];   // fp8 A-tile, double-buffered (8.5 KB)
  __shared__ __align__(16) float xch[16][4][16][4];        // per-wave gate bounce (16 KB)

  const int tid  = threadIdx.x;
  const int lane = tid & 63;
  const int w    = tid >> 6;           // 0..15
  const int nl   = lane & 15;
  const int kq   = lane >> 4;          // MFMA k-quarter; in combine = batch row
  const int dir  = blockIdx.x >> 4;
  const int bg   = blockIdx.x & 15;

  const float* Whh = dir ? Whh_b : Whh_f;
  unsigned short* hbuf = dir ? hb : hf;
  const unsigned short* gxd = gx + (size_t)(dir*16 + bg)*SS*4096;

  // Whh -> fp8 B-fragments in regs: wB[gate][kt] (64 VGPR/lane)
  long wB[4][8];
#pragma unroll
  for (int g = 0; g < 4; ++g)
#pragma unroll
    for (int kt = 0; kt < 8; ++kt){
      int ncol = g*256 + w*16 + nl;
      const float* p = Whh + (size_t)ncol*HH + kt*32 + kq*4;
      float4 lo = *(const float4*)p;
      float4 hi = *(const float4*)(p + 16);
      union { unsigned d[2]; long l; } u;
      u.d[0] = cvt4fp8(lo.x*WSC, lo.y*WSC, lo.z*WSC, lo.w*WSC);
      u.d[1] = cvt4fp8(hi.x*WSC, hi.y*WSC, hi.z*WSC, hi.w*WSC);
      wB[g][kt] = u.l;
    }

  // combine mapping: batch kq, col cc = w*16 + nl
  const int cc = w*16 + nl;
  const int hbyte = (cc >> 5)*32 + ((cc & 15) >> 2)*8 + ((cc & 16) ? 4 : 0) + (cc & 3);

  for (int i = tid; i < 2176; i += 1024) ((unsigned*)h8)[i] = 0;
  __syncthreads();

  float c0 = 0.f;

  unsigned short gxc[4], gxn[4];
  {
    const int t0 = dir ? (SS-1) : 0;
    const unsigned short* gp = gxd + (size_t)t0*4096;
#pragma unroll
    for (int g = 0; g < 4; ++g)
      gxc[g] = gp[(g*256 + cc)*4 + kq];
  }

  for (int s = 0; s < SS; ++s){
    const int t = dir ? (SS-1-s) : s;

    // prefetch next-step gx (retires under MFMA)
    {
      int sn = s + 1;
      int tn = (sn < SS) ? (dir ? (SS-1-sn) : sn) : t;
      const unsigned short* gp = gxd + (size_t)tn*4096;
#pragma unroll
      for (int g = 0; g < 4; ++g)
        gxn[g] = gp[(g*256 + cc)*4 + kq];
    }

    // A-fragments: 8 x ds_read_b64 (rows 4..15 are constant zeros)
    const unsigned char* tp8 = &h8[s & 1][0][0];
    long af[8];
#pragma unroll
    for (int kt = 0; kt < 8; ++kt)
      af[kt] = *(const long*)(tp8 + nl*272 + kt*32 + kq*8);

    f32x4 acc[4];
#pragma unroll
    for (int g = 0; g < 4; ++g) acc[g] = (f32x4){0.f,0.f,0.f,0.f};

#pragma unroll
    for (int kt = 0; kt < 8; ++kt)
#pragma unroll
      for (int g = 0; g < 4; ++g)
        acc[g] = __builtin_amdgcn_mfma_f32_16x16x32_fp8_fp8(af[kt], wB[g][kt], acc[g], 0,0,0);

    // intra-wave gate exchange: lanes with kq==0 hold batch rows 0-3 in regs 0-3
    if (kq == 0){
#pragma unroll
      for (int g = 0; g < 4; ++g)
        *(f32x4*)&xch[w][g][nl][0] = acc[g];     // ds_write_b128, conflict-free
    }
    asm volatile("s_waitcnt lgkmcnt(0)" ::: "memory");

    // combine: lane (batch kq, col cc) -> ONE h value
    {
      const int wslot = dir ? t : (s + 1);
      float i_ = xch[w][0][nl][kq]*ISC + bf2f(gxc[0]);
      float f_ = xch[w][1][nl][kq]*ISC + bf2f(gxc[1]);
      float g_ = xch[w][2][nl][kq]*ISC + bf2f(gxc[2]);
      float o_ = xch[w][3][nl][kq]*ISC + bf2f(gxc[3]);
      float cn = sigm(f_)*c0 + sigm(i_)*ftanh(g_);
      c0 = cn;
      float h = sigm(o_)*ftanh(cn);
      hbuf[(size_t)(wslot*BB + bg*4 + kq)*HH + cc] = f2bf(h);   // global store, not drained in-loop
      h8[(s + 1) & 1][kq][hbyte] = cvt1fp8(h*HSC);              // fp8 into next A-tile
    }

#pragma unroll
    for (int g = 0; g < 4; ++g) gxc[g] = gxn[g];

    // lgkm-only barrier: LDS h8 is the only cross-wave dependency
    asm volatile("s_waitcnt lgkmcnt(0)" ::: "memory");
    __builtin_amdgcn_s_barrier();
    asm volatile("" ::: "memory");
  }
}

// ---------------- FC via MFMA, LDS-staged A (coalesced h reads) ----------------
__global__ __launch_bounds__(256,1) void k_fc(
    const unsigned short* __restrict__ hf, const unsigned short* __restrict__ hb,
    const float* __restrict__ fcW, const float* __restrict__ fcb,
    float* __restrict__ logits)
{
  __shared__ unsigned short Bs[32][516];
  __shared__ unsigned short Ah[4][32][260];
  __shared__ float fcb_s[32];
  const int tid = threadIdx.x;
  for (int i = tid; i < 32*512; i += 256){
    int tg = i >> 9, k = i & 511;
    Bs[tg][k] = f2bf(fcW[tg*512 + k]);
  }
  if (tid < 32) fcb_s[tid] = fcb[tid];
  __syncthreads();

  const int lane = tid & 63, w = tid >> 6;
  const int nl = lane & 15, kq = lane >> 4;
  const int pbase = blockIdx.x * 128;

  f32x4 acc[2][2];
#pragma unroll
  for (int mt = 0; mt < 2; ++mt)
#pragma unroll
    for (int nt = 0; nt < 2; ++nt) acc[mt][nt] = (f32x4){0.f,0.f,0.f,0.f};

  for (int half = 0; half < 2; ++half){
    for (int rr = 0; rr < 32; ++rr){
      int p = pbase + w*32 + rr;
      int t = p >> 6, b = p & 63;
      const unsigned short* src = half ? (hb + (size_t)(t*BB + b)*HH)
                                       : (hf + (size_t)((t+1)*BB + b)*HH);
      *(uint2*)&Ah[w][rr][lane*4] = *(const uint2*)(src + lane*4);
    }
#pragma unroll
    for (int kt = 0; kt < 8; ++kt){
      int kl = kt*32 + kq*4;
      bf16x8 a[2];
#pragma unroll
      for (int mt = 0; mt < 2; ++mt){
        const unsigned short* ar = &Ah[w][mt*16 + nl][kl];
        short4v lo = *(const short4v*)ar;
        short4v hi = *(const short4v*)(ar + 16);
        bf16x8 f = {lo[0],lo[1],lo[2],lo[3],hi[0],hi[1],hi[2],hi[3]};
        a[mt] = f;
      }
#pragma unroll
      for (int nt = 0; nt < 2; ++nt){
        const unsigned short* br = &Bs[nt*16 + nl][half*256 + kl];
        short4v lo = *(const short4v*)br;
        short4v hi = *(const short4v*)(br + 16);
        bf16x8 bv = {lo[0],lo[1],lo[2],lo[3],hi[0],hi[1],hi[2],hi[3]};
        acc[0][nt] = __builtin_amdgcn_mfma_f32_16x16x32_bf16(a[0], bv, acc[0][nt], 0,0,0);
        acc[1][nt] = __builtin_amdgcn_mfma_f32_16x16x32_bf16(a[1], bv, acc[1][nt], 0,0,0);
      }
    }
  }
#pragma unroll
  for (int mt = 0; mt < 2; ++mt)
#pragma unroll
    for (int nt = 0; nt < 2; ++nt)
#pragma unroll
      for (int r = 0; r < 4; ++r){
        int p = pbase + w*32 + mt*16 + kq*4 + r;
        int tg = nt*16 + nl;
        logits[(size_t)p*TT + tg] = acc[mt][nt][r] + fcb_s[tg];
      }
}

// ---------------- merged CRF: blocks 0-15 den, 16-31 vit (LDS hist), 32-47 num ----------------
__global__ void k_crf(const float* __restrict__ logits, const int* __restrict__ mask,
                      const int* __restrict__ labels,
                      const float* __restrict__ start, const float* __restrict__ endt,
                      const float* __restrict__ trans,
                      float* __restrict__ den, float* __restrict__ num,
                      float* __restrict__ preds)
{
  __shared__ float tr[1024];
  __shared__ unsigned char vh_l[4][SS-1][32];
  const int tid = threadIdx.x;
  const int role = blockIdx.x >> 4;
  const int bq   = blockIdx.x & 15;
  if (role != 2){
    for (int i = tid; i < 1024; i += 256) tr[i] = trans[i];
    __syncthreads();
  }
  const int lane = tid & 63, w = tid >> 6;
  const int b = bq*4 + w;
  const int grp = lane >> 5, tp = lane & 31;

  if (role == 0){
    float score = start[tp] + logits[(size_t)b*TT + tp];
    float em_c = logits[(size_t)(BB + b)*TT + tp];
    int   mk_c = mask[b*SS + 1];
    for (int s = 1; s < SS; ++s){
      int sn = (s + 1 < SS) ? s + 1 : s;
      float em_n = logits[(size_t)(sn*BB + b)*TT + tp];
      int   mk_n = mask[b*SS + sn];
      float m = -1e30f;
#pragma unroll
      for (int jj = 0; jj < 16; ++jj){
        int j = grp*16 + jj;
        float v = __shfl(score, j) + tr[j*32 + tp];
        m = fmaxf(m, v);
      }
      m = fmaxf(m, __shfl_xor(m, 32));
      float ssum = 0.f;
#pragma unroll
      for (int jj = 0; jj < 16; ++jj){
        int j = grp*16 + jj;
        float v = __shfl(score, j) + tr[j*32 + tp];
        ssum += __expf(v - m);
      }
      ssum += __shfl_xor(ssum, 32);
      float ns = m + __logf(ssum) + em_c;
      score = mk_c ? ns : score;
      em_c = em_n; mk_c = mk_n;
    }
    float v = score + endt[tp];
    float mm = v;
    for (int d = 1; d < 32; d <<= 1) mm = fmaxf(mm, __shfl_xor(mm, d));
    float se = __expf(v - mm);
    for (int d = 1; d < 32; d <<= 1) se += __shfl_xor(se, d);
    if (lane == 0) den[b] = mm + __logf(se);
  } else if (role == 1){
    float score = start[tp] + logits[(size_t)b*TT + tp];
    float em_c = logits[(size_t)(BB + b)*TT + tp];
    int   mk_c = mask[b*SS + 1];
    for (int s = 1; s < SS; ++s){
      int sn = (s + 1 < SS) ? s + 1 : s;
      float em_n = logits[(size_t)(sn*BB + b)*TT + tp];
      int   mk_n = mask[b*SS + sn];
      float m = -1e30f; int am = 0;
#pragma unroll
      for (int jj = 0; jj < 16; ++jj){
        int j = grp*16 + jj;
        float v = __shfl(score, j) + tr[j*32 + tp];
        if (v > m){ m = v; am = j; }
      }
      float om = __shfl_xor(m, 32); int oam = __shfl_xor(am, 32);
      if (om > m || (om == m && oam < am)){ m = om; am = oam; }
      float ns = m + em_c;
      int idx = mk_c ? am : tp;
      if (grp == 0) vh_l[w][s-1][tp] = (unsigned char)idx;
      score = mk_c ? ns : score;
      em_c = em_n; mk_c = mk_n;
    }
    float v = score + endt[tp]; int a = tp;
    for (int d = 1; d < 32; d <<= 1){
      float ov = __shfl_xor(v, d); int oa = __shfl_xor(a, d);
      if (ov > v || (ov == v && oa < a)){ v = ov; a = oa; }
    }
    int tag = __shfl(a, 0);
    if (lane == 0) preds[(size_t)b*SS + SS - 1] = (float)tag;
    for (int s = SS - 1; s >= 1; --s){
      int rv = vh_l[w][s-1][tp];
      int pv = __shfl(rv, tag);
      if (lane == 0) preds[(size_t)b*SS + s - 1] = (float)pv;
      tag = pv;
    }
  } else {
    float acc = 0.f; int mcnt = 0;
    for (int s = lane; s < SS; s += 64){
      int mk = mask[b*SS + s];
      mcnt += mk;
      if (s >= 1){
        int tg = labels[b*SS + s], tpp = labels[b*SS + s - 1];
        float v = trans[tpp*32 + tg] + logits[(size_t)(s*BB + b)*TT + tg];
        acc += mk ? v : 0.f;
      }
    }
    for (int d = 1; d < 64; d <<= 1){ acc += __shfl_xor(acc, d); mcnt += __shfl_xor(mcnt, d); }
    if (lane == 0){
      int t0 = labels[b*SS];
      int tl = labels[b*SS + (mcnt - 1)];
      num[b] = start[t0] + logits[(size_t)b*TT + t0] + acc + endt[tl];
    }
  }
}

// ---------------- loss ----------------
__global__ void k_loss(const float* __restrict__ num, const float* __restrict__ den,
                       float* __restrict__ out)
{
  int l = threadIdx.x;
  float v = num[l] - den[l];
  for (int d = 1; d < 64; d <<= 1) v += __shfl_xor(v, d);
  if (l == 0) out[BB*SS] = -v;
}

extern "C" void kernel_launch(void* const* d_in, const int* in_sizes, int n_in,
                              void* d_out, int out_size, void* d_ws, size_t ws_size,
                              hipStream_t stream)
{
  const int*   seq       = (const int*)  d_in[0];
  const int*   mask      = (const int*)  d_in[1];
  const int*   labels    = (const int*)  d_in[2];
  const float* embedding = (const float*)d_in[3];
  const float* Wih_f     = (const float*)d_in[4];
  const float* Whh_f     = (const float*)d_in[5];
  const float* bih_f     = (const float*)d_in[6];
  const float* bhh_f     = (const float*)d_in[7];
  const float* Wih_b     = (const float*)d_in[8];
  const float* Whh_b     = (const float*)d_in[9];
  const float* bih_b     = (const float*)d_in[10];
  const float* bhh_b     = (const float*)d_in[11];
  const float* fcW       = (const float*)d_in[12];
  const float* fcb       = (const float*)d_in[13];
  const float* start_t   = (const float*)d_in[14];
  const float* end_t     = (const float*)d_in[15];
  const float* trans     = (const float*)d_in[16];

  char* ws = (char*)d_ws;
  size_t off = 0;
  unsigned short* gxb = (unsigned short*)(ws + off); off += (size_t)2*SS*1024*64*2;     // 128 MiB
  unsigned short* hf  = (unsigned short*)(ws + off); off += (size_t)(SS+1)*BB*HH*2;     // 16 MiB
  unsigned short* hb  = (unsigned short*)(ws + off); off += (size_t)(SS+1)*BB*HH*2;     // 16 MiB
  float*          lgt = (float*)(ws + off);          off += (size_t)SS*BB*TT*4;         // 4 MiB
  float*          den = (float*)(ws + off);          off += 256;
  float*          num = (float*)(ws + off);          off += 256;

  k_xgemm<<<dim3(256,2), 256, 0, stream>>>(seq, embedding, Wih_f, Wih_b,
                                           bih_f, bhh_f, bih_b, bhh_b, gxb);
  k_lstm<<<32, 1024, 0, stream>>>(gxb, Whh_f, Whh_b, hf, hb);
  k_fc<<<256, 256, 0, stream>>>(hf, hb, fcW, fcb, lgt);
  k_crf<<<48, 256, 0, stream>>>(lgt, mask, labels, start_t, end_t, trans, den, num, (float*)d_out);
  k_loss<<<1, 64, 0, stream>>>(num, den, (float*)d_out);
}

// Round 14
// 1385.430 us; speedup vs baseline: 1.9429x; 1.0403x over previous
//
#include <hip/hip_runtime.h>
#include <stdint.h>

#define SS 512
#define BB 64
#define HH 256
#define TT 32

typedef __attribute__((ext_vector_type(8))) short bf16x8;
typedef __attribute__((ext_vector_type(4))) short short4v;
typedef __attribute__((ext_vector_type(4))) float f32x4;
typedef __attribute__((ext_vector_type(8))) int i32x8;
typedef __attribute__((ext_vector_type(4))) int i32x4;

__device__ __forceinline__ unsigned short f2bf(float f){
  unsigned u = __float_as_uint(f);
  unsigned r = (u + 0x7FFFu + ((u >> 16) & 1u)) >> 16;
  return (unsigned short)r;
}
__device__ __forceinline__ float bf2f(unsigned short s){
  return __uint_as_float(((unsigned)s) << 16);
}
__device__ __forceinline__ float sigm(float x){ return 1.0f/(1.0f+__expf(-x)); }
__device__ __forceinline__ float ftanh(float x){
  float e = __expf(2.f*x);
  return 1.f - 2.f/(e + 1.f);
}
__device__ __forceinline__ unsigned cvt4fp8(float a0, float a1, float a2, float a3){
  int d = __builtin_amdgcn_cvt_pk_fp8_f32(a0, a1, 0, false);
  d = __builtin_amdgcn_cvt_pk_fp8_f32(a2, a3, d, true);
  return (unsigned)d;
}
__device__ __forceinline__ unsigned short cvt2fp8(float a0, float a1){
  int d = __builtin_amdgcn_cvt_pk_fp8_f32(a0, a1, 0, false);
  return (unsigned short)(d & 0xFFFF);
}

// swizzled-LDS fragment read (used by k_xgemm only)
__device__ __forceinline__ bf16x8 afrag(const unsigned short* A, int mt, int ktp, int nl, int kq){
  int m = mt*16 + nl;
  int sw = (m & 7) << 3;
  int kk = ktp*32 + kq*4;
  short4v lo = *(const short4v*)(A + (m << 8) + (kk ^ sw));
  short4v hi = *(const short4v*)(A + (m << 8) + ((kk + 16) ^ sw));
  bf16x8 r = {lo[0],lo[1],lo[2],lo[3],hi[0],hi[1],hi[2],hi[3]};
  return r;
}

// ---------------- fused gather + x@Wih^T GEMM (+bias fold) -> gx bf16 [dir*16+bg][t][col][b4] ----------------
__global__ __launch_bounds__(256,1) void k_xgemm(
    const int* __restrict__ seq, const float* __restrict__ emb,
    const float* __restrict__ Wih_f, const float* __restrict__ Wih_b,
    const float* __restrict__ bih_f, const float* __restrict__ bhh_f,
    const float* __restrict__ bih_b, const float* __restrict__ bhh_b,
    unsigned short* __restrict__ gx)
{
  __shared__ __align__(16) unsigned short A_l[128*256];  // 64 KiB
  __shared__ __align__(16) unsigned short B_l[64*256];   // 32 KiB

  const int tid = threadIdx.x;
  const int lane = tid & 63, w = tid >> 6;
  const int nl = lane & 15, kq = lane >> 4;
  const int pbase = blockIdx.x * 128;
  const int dir = blockIdx.y;
  const float* Wih  = dir ? Wih_b : Wih_f;
  const float* bihd = dir ? bih_b : bih_f;
  const float* bhhd = dir ? bhh_b : bhh_f;

#pragma unroll
  for (int i = 0; i < 16; ++i){
    int c = tid + i*256;
    int m = c >> 5, k8 = c & 31;
    int p = pbase + m, t = p >> 6, b = p & 63;
    int er = seq[b*SS + t];
    const float* s = emb + (size_t)er*HH + k8*8;
    float4 x0 = *(const float4*)s, x1 = *(const float4*)(s+4);
    union { unsigned short u[8]; uint4 v; } o;
    o.u[0]=f2bf(x0.x); o.u[1]=f2bf(x0.y); o.u[2]=f2bf(x0.z); o.u[3]=f2bf(x0.w);
    o.u[4]=f2bf(x1.x); o.u[5]=f2bf(x1.y); o.u[6]=f2bf(x1.z); o.u[7]=f2bf(x1.w);
    *(uint4*)&A_l[(m << 8) + ((k8*8) ^ ((m & 7) << 3))] = o.v;
  }

  for (int nb = 0; nb < 16; ++nb){
    __syncthreads();
#pragma unroll
    for (int i = 0; i < 8; ++i){
      int c = tid + i*256;
      int m = c >> 5, k8 = c & 31;
      const float* s = Wih + (size_t)(nb*64 + m)*HH + k8*8;
      float4 x0 = *(const float4*)s, x1 = *(const float4*)(s+4);
      union { unsigned short u[8]; uint4 v; } o;
      o.u[0]=f2bf(x0.x); o.u[1]=f2bf(x0.y); o.u[2]=f2bf(x0.z); o.u[3]=f2bf(x0.w);
      o.u[4]=f2bf(x1.x); o.u[5]=f2bf(x1.y); o.u[6]=f2bf(x1.z); o.u[7]=f2bf(x1.w);
      *(uint4*)&B_l[(m << 8) + ((k8*8) ^ ((m & 7) << 3))] = o.v;
    }
    __syncthreads();

    f32x4 acc[2][4];
#pragma unroll
    for (int mt = 0; mt < 2; ++mt)
#pragma unroll
      for (int nt = 0; nt < 4; ++nt) acc[mt][nt] = (f32x4){0.f,0.f,0.f,0.f};

#pragma unroll
    for (int kt = 0; kt < 8; ++kt){
      bf16x8 a0 = afrag(A_l, w*2+0, kt, nl, kq);
      bf16x8 a1 = afrag(A_l, w*2+1, kt, nl, kq);
#pragma unroll
      for (int nt = 0; nt < 4; ++nt){
        bf16x8 bv = afrag(B_l, nt, kt, nl, kq);
        acc[0][nt] = __builtin_amdgcn_mfma_f32_16x16x32_bf16(a0, bv, acc[0][nt], 0,0,0);
        acc[1][nt] = __builtin_amdgcn_mfma_f32_16x16x32_bf16(a1, bv, acc[1][nt], 0,0,0);
      }
    }

#pragma unroll
    for (int mt = 0; mt < 2; ++mt)
#pragma unroll
      for (int nt = 0; nt < 4; ++nt){
        int p0 = pbase + w*32 + mt*16 + kq*4;
        int t = p0 >> 6, b0 = p0 & 63;
        int col = nb*64 + nt*16 + nl;
        float bs = bihd[col] + bhhd[col];      // bias folded into gx
        union { unsigned short u[4]; uint2 v; } o;
        o.u[0]=f2bf(acc[mt][nt][0] + bs); o.u[1]=f2bf(acc[mt][nt][1] + bs);
        o.u[2]=f2bf(acc[mt][nt][2] + bs); o.u[3]=f2bf(acc[mt][nt][3] + bs);
        *(uint2*)(gx + ((size_t)(dir*16 + (b0 >> 2))*SS + t)*4096 + col*4) = o.v;
      }
  }
}

// ---------------- LSTM: 32 blocks x 1024 threads, MX-scaled K=128 fp8 MFMA ----------------
// Wave w (0..15): all 4 gates for cols w*16..+15. Whh fp8 in regs (64 VGPR as 2x i32x8/gate).
// A-tile LINEAR fp8 [16 rows][256 k]+pad; lane(nl=row, kq=k-chunk) reads 32B contiguous.
// Unit E8M0 scales (0x7F) -> pure fp8 matmul at MX rate; WSC/HSC static scaling kept.
#define WSC 64.0f
#define HSC 16.0f
#define ISC (1.0f/(WSC*HSC))

__global__ __launch_bounds__(1024,1) void k_lstm(
    const unsigned short* __restrict__ gx,
    const float* __restrict__ Whh_f, const float* __restrict__ Whh_b,
    unsigned short* __restrict__ hf, unsigned short* __restrict__ hb)
{
  __shared__ __align__(16) unsigned char h8[2][16][272];   // linear fp8 A-tile, dbuf (8.5 KB)
  __shared__ __align__(16) float xch[16][4][16][4];        // per-wave gate bounce (16 KB)

  const int tid  = threadIdx.x;
  const int lane = tid & 63;
  const int w    = tid >> 6;           // 0..15
  const int nl   = lane & 15;
  const int kq   = lane >> 4;
  const int dir  = blockIdx.x >> 4;
  const int bg   = blockIdx.x & 15;

  const float* Whh = dir ? Whh_b : Whh_f;
  unsigned short* hbuf = dir ? hb : hf;
  const unsigned short* gxd = gx + (size_t)(dir*16 + bg)*SS*4096;

  // Whh -> fp8 B-fragments: wB[gate][inst] = i32x8; dword d covers k = inst*128 + kq*32 + d*4 +[0..3]
  i32x8 wB[4][2];
#pragma unroll
  for (int g = 0; g < 4; ++g)
#pragma unroll
    for (int inst = 0; inst < 2; ++inst){
      int ncol = g*256 + w*16 + nl;
      i32x8 bfrag;
#pragma unroll
      for (int d = 0; d < 8; ++d){
        int k0 = inst*128 + kq*32 + d*4;
        float4 v = *(const float4*)(Whh + (size_t)ncol*HH + k0);
        bfrag[d] = (int)cvt4fp8(v.x*WSC, v.y*WSC, v.z*WSC, v.w*WSC);
      }
      wB[g][inst] = bfrag;
    }

  // combine mapping: batch kq, col cc = w*16 + nl
  const int cc = w*16 + nl;

  for (int i = tid; i < 2176; i += 1024) ((unsigned*)h8)[i] = 0;
  __syncthreads();

  float c0 = 0.f;

  // loop-invariant addresses
  const int aoff = nl*272 + kq*32;                 // A-frag read (row nl, k-chunk kq)
  const int woff = kq*272 + w*16 + nl;             // h8 write (row kq, col cc)
  const ptrdiff_t gstep = dir ? -4096 : 4096;
  const unsigned short* gbase = gxd + (size_t)(dir ? (SS-1) : 0)*4096 + cc*4 + kq;
  unsigned short* hstore = hbuf + (size_t)(dir ? (SS-1) : 1)*BB*HH + (size_t)(bg*4 + kq)*HH + cc;
  const ptrdiff_t hstep = (dir ? -(ptrdiff_t)1 : (ptrdiff_t)1)*BB*HH;

  unsigned short gxc[4], gxn[4];
#pragma unroll
  for (int g = 0; g < 4; ++g) gxc[g] = gbase[g*1024];

  for (int s = 0; s < SS; ++s){
    // prefetch next-step gx via pointer increment (retires under MFMA)
    const unsigned short* gnext = (s + 1 < SS) ? (gbase + gstep) : gbase;
#pragma unroll
    for (int g = 0; g < 4; ++g) gxn[g] = gnext[g*1024];

    // A-fragments: 2 insts x 32B contiguous (2x ds_read_b128 each)
    const unsigned char* tp8 = &h8[s & 1][0][0] + aoff;
    i32x8 af0, af1;
    {
      i32x4 lo = *(const i32x4*)(tp8);
      i32x4 hi = *(const i32x4*)(tp8 + 16);
      af0 = (i32x8){lo[0],lo[1],lo[2],lo[3],hi[0],hi[1],hi[2],hi[3]};
      i32x4 lo2 = *(const i32x4*)(tp8 + 128);
      i32x4 hi2 = *(const i32x4*)(tp8 + 144);
      af1 = (i32x8){lo2[0],lo2[1],lo2[2],lo2[3],hi2[0],hi2[1],hi2[2],hi2[3]};
    }

    f32x4 acc[4];
#pragma unroll
    for (int g = 0; g < 4; ++g) acc[g] = (f32x4){0.f,0.f,0.f,0.f};

#pragma unroll
    for (int g = 0; g < 4; ++g)
      acc[g] = __builtin_amdgcn_mfma_scale_f32_16x16x128_f8f6f4(
                 af0, wB[g][0], acc[g], 0, 0, 0, 0x7F7F7F7F, 0, 0x7F7F7F7F);
#pragma unroll
    for (int g = 0; g < 4; ++g)
      acc[g] = __builtin_amdgcn_mfma_scale_f32_16x16x128_f8f6f4(
                 af1, wB[g][1], acc[g], 0, 0, 0, 0x7F7F7F7F, 0, 0x7F7F7F7F);

    // intra-wave gate exchange: kq==0 lanes hold batch rows 0-3 in regs 0-3
    if (kq == 0){
#pragma unroll
      for (int g = 0; g < 4; ++g)
        *(f32x4*)&xch[w][g][nl][0] = acc[g];     // ds_write_b128
    }
    asm volatile("s_waitcnt lgkmcnt(0)" ::: "memory");

    // combine: lane (batch kq, col cc) -> ONE h value
    {
      float i_ = xch[w][0][nl][kq]*ISC + bf2f(gxc[0]);
      float f_ = xch[w][1][nl][kq]*ISC + bf2f(gxc[1]);
      float g_ = xch[w][2][nl][kq]*ISC + bf2f(gxc[2]);
      float o_ = xch[w][3][nl][kq]*ISC + bf2f(gxc[3]);
      float cn = sigm(f_)*c0 + sigm(i_)*ftanh(g_);
      c0 = cn;
      float h = sigm(o_)*ftanh(cn);

      // cross-lane pack: fp8 dword per 4 lanes, bf16 dword per 2 lanes
      float s1 = __shfl_xor(h, 1);
      unsigned short p01 = cvt2fp8(h*HSC, s1*HSC);          // valid on even nl
      unsigned p23 = __shfl_xor((unsigned)p01, 2);          // even nl: pair from nl+2
      if ((nl & 3) == 0){
        unsigned word = (unsigned)p01 | (p23 << 16);        // bytes h(nl..nl+3)
        *(unsigned*)(&h8[(s + 1) & 1][0][0] + woff) = word;
      }
      if (!(nl & 1)){
        unsigned hv;
        asm volatile("v_cvt_pk_bf16_f32 %0, %1, %2" : "=v"(hv) : "v"(h), "v"(s1));
        *(unsigned*)hstore = hv;                            // cols cc, cc+1
      }
    }

#pragma unroll
    for (int g = 0; g < 4; ++g) gxc[g] = gxn[g];
    gbase = gnext;
    hstore += hstep;

    // lgkm-only barrier: LDS h8 is the only cross-wave dependency
    asm volatile("s_waitcnt lgkmcnt(0)" ::: "memory");
    __builtin_amdgcn_s_barrier();
    asm volatile("" ::: "memory");
  }
}

// ---------------- FC via MFMA, LDS-staged A (coalesced h reads) ----------------
__global__ __launch_bounds__(256,1) void k_fc(
    const unsigned short* __restrict__ hf, const unsigned short* __restrict__ hb,
    const float* __restrict__ fcW, const float* __restrict__ fcb,
    float* __restrict__ logits)
{
  __shared__ unsigned short Bs[32][516];
  __shared__ unsigned short Ah[4][32][260];
  __shared__ float fcb_s[32];
  const int tid = threadIdx.x;
  for (int i = tid; i < 32*512; i += 256){
    int tg = i >> 9, k = i & 511;
    Bs[tg][k] = f2bf(fcW[tg*512 + k]);
  }
  if (tid < 32) fcb_s[tid] = fcb[tid];
  __syncthreads();

  const int lane = tid & 63, w = tid >> 6;
  const int nl = lane & 15, kq = lane >> 4;
  const int pbase = blockIdx.x * 128;

  f32x4 acc[2][2];
#pragma unroll
  for (int mt = 0; mt < 2; ++mt)
#pragma unroll
    for (int nt = 0; nt < 2; ++nt) acc[mt][nt] = (f32x4){0.f,0.f,0.f,0.f};

  for (int half = 0; half < 2; ++half){
    for (int rr = 0; rr < 32; ++rr){
      int p = pbase + w*32 + rr;
      int t = p >> 6, b = p & 63;
      const unsigned short* src = half ? (hb + (size_t)(t*BB + b)*HH)
                                       : (hf + (size_t)((t+1)*BB + b)*HH);
      *(uint2*)&Ah[w][rr][lane*4] = *(const uint2*)(src + lane*4);
    }
#pragma unroll
    for (int kt = 0; kt < 8; ++kt){
      int kl = kt*32 + kq*4;
      bf16x8 a[2];
#pragma unroll
      for (int mt = 0; mt < 2; ++mt){
        const unsigned short* ar = &Ah[w][mt*16 + nl][kl];
        short4v lo = *(const short4v*)ar;
        short4v hi = *(const short4v*)(ar + 16);
        bf16x8 f = {lo[0],lo[1],lo[2],lo[3],hi[0],hi[1],hi[2],hi[3]};
        a[mt] = f;
      }
#pragma unroll
      for (int nt = 0; nt < 2; ++nt){
        const unsigned short* br = &Bs[nt*16 + nl][half*256 + kl];
        short4v lo = *(const short4v*)br;
        short4v hi = *(const short4v*)(br + 16);
        bf16x8 bv = {lo[0],lo[1],lo[2],lo[3],hi[0],hi[1],hi[2],hi[3]};
        acc[0][nt] = __builtin_amdgcn_mfma_f32_16x16x32_bf16(a[0], bv, acc[0][nt], 0,0,0);
        acc[1][nt] = __builtin_amdgcn_mfma_f32_16x16x32_bf16(a[1], bv, acc[1][nt], 0,0,0);
      }
    }
  }
#pragma unroll
  for (int mt = 0; mt < 2; ++mt)
#pragma unroll
    for (int nt = 0; nt < 2; ++nt)
#pragma unroll
      for (int r = 0; r < 4; ++r){
        int p = pbase + w*32 + mt*16 + kq*4 + r;
        int tg = nt*16 + nl;
        logits[(size_t)p*TT + tg] = acc[mt][nt][r] + fcb_s[tg];
      }
}

// ---------------- merged CRF: blocks 0-15 den, 16-31 vit (LDS hist), 32-47 num ----------------
__global__ void k_crf(const float* __restrict__ logits, const int* __restrict__ mask,
                      const int* __restrict__ labels,
                      const float* __restrict__ start, const float* __restrict__ endt,
                      const float* __restrict__ trans,
                      float* __restrict__ den, float* __restrict__ num,
                      float* __restrict__ preds)
{
  __shared__ float tr[1024];
  __shared__ unsigned char vh_l[4][SS-1][32];
  const int tid = threadIdx.x;
  const int role = blockIdx.x >> 4;
  const int bq   = blockIdx.x & 15;
  if (role != 2){
    for (int i = tid; i < 1024; i += 256) tr[i] = trans[i];
    __syncthreads();
  }
  const int lane = tid & 63, w = tid >> 6;
  const int b = bq*4 + w;
  const int grp = lane >> 5, tp = lane & 31;

  if (role == 0){
    float score = start[tp] + logits[(size_t)b*TT + tp];
    float em_c = logits[(size_t)(BB + b)*TT + tp];
    int   mk_c = mask[b*SS + 1];
    for (int s = 1; s < SS; ++s){
      int sn = (s + 1 < SS) ? s + 1 : s;
      float em_n = logits[(size_t)(sn*BB + b)*TT + tp];
      int   mk_n = mask[b*SS + sn];
      float m = -1e30f;
#pragma unroll
      for (int jj = 0; jj < 16; ++jj){
        int j = grp*16 + jj;
        float v = __shfl(score, j) + tr[j*32 + tp];
        m = fmaxf(m, v);
      }
      m = fmaxf(m, __shfl_xor(m, 32));
      float ssum = 0.f;
#pragma unroll
      for (int jj = 0; jj < 16; ++jj){
        int j = grp*16 + jj;
        float v = __shfl(score, j) + tr[j*32 + tp];
        ssum += __expf(v - m);
      }
      ssum += __shfl_xor(ssum, 32);
      float ns = m + __logf(ssum) + em_c;
      score = mk_c ? ns : score;
      em_c = em_n; mk_c = mk_n;
    }
    float v = score + endt[tp];
    float mm = v;
    for (int d = 1; d < 32; d <<= 1) mm = fmaxf(mm, __shfl_xor(mm, d));
    float se = __expf(v - mm);
    for (int d = 1; d < 32; d <<= 1) se += __shfl_xor(se, d);
    if (lane == 0) den[b] = mm + __logf(se);
  } else if (role == 1){
    float score = start[tp] + logits[(size_t)b*TT + tp];
    float em_c = logits[(size_t)(BB + b)*TT + tp];
    int   mk_c = mask[b*SS + 1];
    for (int s = 1; s < SS; ++s){
      int sn = (s + 1 < SS) ? s + 1 : s;
      float em_n = logits[(size_t)(sn*BB + b)*TT + tp];
      int   mk_n = mask[b*SS + sn];
      float m = -1e30f; int am = 0;
#pragma unroll
      for (int jj = 0; jj < 16; ++jj){
        int j = grp*16 + jj;
        float v = __shfl(score, j) + tr[j*32 + tp];
        if (v > m){ m = v; am = j; }
      }
      float om = __shfl_xor(m, 32); int oam = __shfl_xor(am, 32);
      if (om > m || (om == m && oam < am)){ m = om; am = oam; }
      float ns = m + em_c;
      int idx = mk_c ? am : tp;
      if (grp == 0) vh_l[w][s-1][tp] = (unsigned char)idx;
      score = mk_c ? ns : score;
      em_c = em_n; mk_c = mk_n;
    }
    float v = score + endt[tp]; int a = tp;
    for (int d = 1; d < 32; d <<= 1){
      float ov = __shfl_xor(v, d); int oa = __shfl_xor(a, d);
      if (ov > v || (ov == v && oa < a)){ v = ov; a = oa; }
    }
    int tag = __shfl(a, 0);
    if (lane == 0) preds[(size_t)b*SS + SS - 1] = (float)tag;
    for (int s = SS - 1; s >= 1; --s){
      int rv = vh_l[w][s-1][tp];
      int pv = __shfl(rv, tag);
      if (lane == 0) preds[(size_t)b*SS + s - 1] = (float)pv;
      tag = pv;
    }
  } else {
    float acc = 0.f; int mcnt = 0;
    for (int s = lane; s < SS; s += 64){
      int mk = mask[b*SS + s];
      mcnt += mk;
      if (s >= 1){
        int tg = labels[b*SS + s], tpp = labels[b*SS + s - 1];
        float v = trans[tpp*32 + tg] + logits[(size_t)(s*BB + b)*TT + tg];
        acc += mk ? v : 0.f;
      }
    }
    for (int d = 1; d < 64; d <<= 1){ acc += __shfl_xor(acc, d); mcnt += __shfl_xor(mcnt, d); }
    if (lane == 0){
      int t0 = labels[b*SS];
      int tl = labels[b*SS + (mcnt - 1)];
      num[b] = start[t0] + logits[(size_t)b*TT + t0] + acc + endt[tl];
    }
  }
}

// ---------------- loss ----------------
__global__ void k_loss(const float* __restrict__ num, const float* __restrict__ den,
                       float* __restrict__ out)
{
  int l = threadIdx.x;
  float v = num[l] - den[l];
  for (int d = 1; d < 64; d <<= 1) v += __shfl_xor(v, d);
  if (l == 0) out[BB*SS] = -v;
}

extern "C" void kernel_launch(void* const* d_in, const int* in_sizes, int n_in,
                              void* d_out, int out_size, void* d_ws, size_t ws_size,
                              hipStream_t stream)
{
  const int*   seq       = (const int*)  d_in[0];
  const int*   mask      = (const int*)  d_in[1];
  const int*   labels    = (const int*)  d_in[2];
  const float* embedding = (const float*)d_in[3];
  const float* Wih_f     = (const float*)d_in[4];
  const float* Whh_f     = (const float*)d_in[5];
  const float* bih_f     = (const float*)d_in[6];
  const float* bhh_f     = (const float*)d_in[7];
  const float* Wih_b     = (const float*)d_in[8];
  const float* Whh_b     = (const float*)d_in[9];
  const float* bih_b     = (const float*)d_in[10];
  const float* bhh_b     = (const float*)d_in[11];
  const float* fcW       = (const float*)d_in[12];
  const float* fcb       = (const float*)d_in[13];
  const float* start_t   = (const float*)d_in[14];
  const float* end_t     = (const float*)d_in[15];
  const float* trans     = (const float*)d_in[16];

  char* ws = (char*)d_ws;
  size_t off = 0;
  unsigned short* gxb = (unsigned short*)(ws + off); off += (size_t)2*SS*1024*64*2;     // 128 MiB
  unsigned short* hf  = (unsigned short*)(ws + off); off += (size_t)(SS+1)*BB*HH*2;     // 16 MiB
  unsigned short* hb  = (unsigned short*)(ws + off); off += (size_t)(SS+1)*BB*HH*2;     // 16 MiB
  float*          lgt = (float*)(ws + off);          off += (size_t)SS*BB*TT*4;         // 4 MiB
  float*          den = (float*)(ws + off);          off += 256;
  float*          num = (float*)(ws + off);          off += 256;

  k_xgemm<<<dim3(256,2), 256, 0, stream>>>(seq, embedding, Wih_f, Wih_b,
                                           bih_f, bhh_f, bih_b, bhh_b, gxb);
  k_lstm<<<32, 1024, 0, stream>>>(gxb, Whh_f, Whh_b, hf, hb);
  k_fc<<<256, 256, 0, stream>>>(hf, hb, fcW, fcb, lgt);
  k_crf<<<48, 256, 0, stream>>>(lgt, mask, labels, start_t, end_t, trans, den, num, (float*)d_out);
  k_loss<<<1, 64, 0, stream>>>(num, den, (float*)d_out);
}

// Round 15
// 1255.628 us; speedup vs baseline: 2.1438x; 1.1034x over previous
//
#include <hip/hip_runtime.h>
#include <stdint.h>

#define SS 512
#define BB 64
#define HH 256
#define TT 32

typedef __attribute__((ext_vector_type(8))) short bf16x8;
typedef __attribute__((ext_vector_type(4))) short short4v;
typedef __attribute__((ext_vector_type(4))) float f32x4;
typedef __attribute__((ext_vector_type(8))) int i32x8;
typedef __attribute__((ext_vector_type(4))) int i32x4;

__device__ __forceinline__ unsigned short f2bf(float f){
  unsigned u = __float_as_uint(f);
  unsigned r = (u + 0x7FFFu + ((u >> 16) & 1u)) >> 16;
  return (unsigned short)r;
}
__device__ __forceinline__ float bf2f(unsigned short s){
  return __uint_as_float(((unsigned)s) << 16);
}
__device__ __forceinline__ float sigm(float x){ return 1.0f/(1.0f+__expf(-x)); }
__device__ __forceinline__ float ftanh(float x){
  float e = __expf(2.f*x);
  return 1.f - 2.f/(e + 1.f);
}
__device__ __forceinline__ unsigned cvt4fp8(float a0, float a1, float a2, float a3){
  int d = __builtin_amdgcn_cvt_pk_fp8_f32(a0, a1, 0, false);
  d = __builtin_amdgcn_cvt_pk_fp8_f32(a2, a3, d, true);
  return (unsigned)d;
}
__device__ __forceinline__ unsigned short cvt2fp8(float a0, float a1){
  int d = __builtin_amdgcn_cvt_pk_fp8_f32(a0, a1, 0, false);
  return (unsigned short)(d & 0xFFFF);
}

// swizzled-LDS fragment read (producer role)
__device__ __forceinline__ bf16x8 afrag(const unsigned short* A, int mt, int ktp, int nl, int kq){
  int m = mt*16 + nl;
  int sw = (m & 7) << 3;
  int kk = ktp*32 + kq*4;
  short4v lo = *(const short4v*)(A + (m << 8) + (kk ^ sw));
  short4v hi = *(const short4v*)(A + (m << 8) + ((kk + 16) ^ sw));
  bf16x8 r = {lo[0],lo[1],lo[2],lo[3],hi[0],hi[1],hi[2],hi[3]};
  return r;
}

#define WSC 64.0f
#define HSC 16.0f
#define ISC (1.0f/(WSC*HSC))

// ================= fused producer(xgemm) / consumer(lstm) kernel =================
// blocks 0..31: LSTM consumers (dir = b>>4, bg = b&15), resident first.
// blocks 32..2079: producers. e = b-32: dir=e&1, xi=(e>>1)>>2, ch=(e>>1)&3.
//   xe = dir? 255-xi : xi  -> produces t-pair {2xe, 2xe+1}, n-cols ch*256..+255.
//   Flag[dir*256+xe] counts 4 chunk-blocks; gx + flags via MALL-coherent (sc1) ops.
__global__ __launch_bounds__(1024,1) void k_fused(
    const int* __restrict__ seq, const float* __restrict__ emb,
    const float* __restrict__ Wih_f, const float* __restrict__ Wih_b,
    const float* __restrict__ bih_f, const float* __restrict__ bhh_f,
    const float* __restrict__ bih_b, const float* __restrict__ bhh_b,
    const float* __restrict__ Whh_f, const float* __restrict__ Whh_b,
    unsigned short* __restrict__ gx,
    unsigned short* __restrict__ hf, unsigned short* __restrict__ hb,
    unsigned int* flags)
{
  __shared__ __align__(16) unsigned char smem[98304];
  const int tid  = threadIdx.x;
  const int lane = tid & 63;
  const int w    = tid >> 6;           // 0..15
  const int nl   = lane & 15;
  const int kq   = lane >> 4;

  if (blockIdx.x >= 32){
    // ---------------- producer role ----------------
    unsigned short* A_l = (unsigned short*)smem;            // 128x256 bf16 (64 KB)
    unsigned short* B_l = (unsigned short*)(smem + 65536);  // 64x256 bf16 (32 KB)
    const int e    = blockIdx.x - 32;
    const int dir  = e & 1;
    const int rest = e >> 1;
    const int xi   = rest >> 2;
    const int ch   = rest & 3;
    const int xe   = dir ? (255 - xi) : xi;
    const int pbase = xe * 128;
    const float* Wih  = dir ? Wih_b : Wih_f;
    const float* bihd = dir ? bih_b : bih_f;
    const float* bhhd = dir ? bhh_b : bhh_f;
    const int m8 = w & 7, nh = w >> 3;

    // stage A: 128 rows (p = t*64+b), embedding gather f32->bf16, swizzled
#pragma unroll
    for (int i = 0; i < 4; ++i){
      int c = tid + i*1024;
      int m = c >> 5, k8 = c & 31;
      int p = pbase + m, t = p >> 6, b = p & 63;
      int er = seq[b*SS + t];
      const float* s = emb + (size_t)er*HH + k8*8;
      float4 x0 = *(const float4*)s, x1 = *(const float4*)(s+4);
      union { unsigned short u[8]; uint4 v; } o;
      o.u[0]=f2bf(x0.x); o.u[1]=f2bf(x0.y); o.u[2]=f2bf(x0.z); o.u[3]=f2bf(x0.w);
      o.u[4]=f2bf(x1.x); o.u[5]=f2bf(x1.y); o.u[6]=f2bf(x1.z); o.u[7]=f2bf(x1.w);
      *(uint4*)&A_l[(m << 8) + ((k8*8) ^ ((m & 7) << 3))] = o.v;
    }

    for (int nq = 0; nq < 4; ++nq){
      const int nb = ch*4 + nq;
      __syncthreads();
#pragma unroll
      for (int i = 0; i < 2; ++i){
        int c = tid + i*1024;
        int m = c >> 5, k8 = c & 31;
        const float* s = Wih + (size_t)(nb*64 + m)*HH + k8*8;
        float4 x0 = *(const float4*)s, x1 = *(const float4*)(s+4);
        union { unsigned short u[8]; uint4 v; } o;
        o.u[0]=f2bf(x0.x); o.u[1]=f2bf(x0.y); o.u[2]=f2bf(x0.z); o.u[3]=f2bf(x0.w);
        o.u[4]=f2bf(x1.x); o.u[5]=f2bf(x1.y); o.u[6]=f2bf(x1.z); o.u[7]=f2bf(x1.w);
        *(uint4*)&B_l[(m << 8) + ((k8*8) ^ ((m & 7) << 3))] = o.v;
      }
      __syncthreads();

      f32x4 acc0 = {0.f,0.f,0.f,0.f}, acc1 = acc0;
#pragma unroll
      for (int kt = 0; kt < 8; ++kt){
        bf16x8 a0 = afrag(A_l, m8, kt, nl, kq);
        bf16x8 b0 = afrag(B_l, nh*2 + 0, kt, nl, kq);
        bf16x8 b1 = afrag(B_l, nh*2 + 1, kt, nl, kq);
        acc0 = __builtin_amdgcn_mfma_f32_16x16x32_bf16(a0, b0, acc0, 0,0,0);
        acc1 = __builtin_amdgcn_mfma_f32_16x16x32_bf16(a0, b1, acc1, 0,0,0);
      }

      const int p0 = pbase + m8*16 + kq*4;
      const int t = p0 >> 6, b0 = p0 & 63;
#pragma unroll
      for (int ntl = 0; ntl < 2; ++ntl){
        int col = nb*64 + (nh*2 + ntl)*16 + nl;
        float bs = bihd[col] + bhhd[col];
        f32x4 A = ntl ? acc1 : acc0;
        union { unsigned short u[4]; unsigned long long ll; } o;
        o.u[0]=f2bf(A[0]+bs); o.u[1]=f2bf(A[1]+bs);
        o.u[2]=f2bf(A[2]+bs); o.u[3]=f2bf(A[3]+bs);
        __hip_atomic_store(
          (unsigned long long*)(gx + ((size_t)(dir*16 + (b0 >> 2))*SS + t)*4096 + col*4),
          o.ll, __ATOMIC_RELAXED, __HIP_MEMORY_SCOPE_AGENT);
      }
    }
    __syncthreads();   // drains all waves' stores (vmcnt 0 before barrier)
    if (tid == 0)
      __hip_atomic_fetch_add(&flags[dir*256 + xe], 1u,
                             __ATOMIC_RELAXED, __HIP_MEMORY_SCOPE_AGENT);
    return;
  }

  // ---------------- consumer role: LSTM (R14 structure) ----------------
  unsigned char* h8b = smem;                                   // [2][16][272] = 8704 B
  float (*xch)[4][16][4] = (float(*)[4][16][4])(smem + 8704);  // [16][4][16][4] = 16 KB
  int* s_clear = (int*)(smem + 8704 + 16384);

  const int dir = blockIdx.x >> 4;
  const int bg  = blockIdx.x & 15;
  const float* Whh = dir ? Whh_b : Whh_f;
  unsigned short* hbuf = dir ? hb : hf;
  const unsigned short* gxd = gx + (size_t)(dir*16 + bg)*SS*4096;
  const unsigned int* flg = flags + dir*256;

  // Whh -> fp8 B-fragments (MX K=128): wB[gate][inst]
  i32x8 wB[4][2];
#pragma unroll
  for (int g = 0; g < 4; ++g)
#pragma unroll
    for (int inst = 0; inst < 2; ++inst){
      int ncol = g*256 + w*16 + nl;
      i32x8 bfrag;
#pragma unroll
      for (int d = 0; d < 8; ++d){
        int k0 = inst*128 + kq*32 + d*4;
        float4 v = *(const float4*)(Whh + (size_t)ncol*HH + k0);
        bfrag[d] = (int)cvt4fp8(v.x*WSC, v.y*WSC, v.z*WSC, v.w*WSC);
      }
      wB[g][inst] = bfrag;
    }

  const int cc = w*16 + nl;
  for (int i = tid; i < 2176; i += 1024) ((unsigned*)h8b)[i] = 0;
  if (tid == 0) *s_clear = 0;
  __syncthreads();

  float c0 = 0.f;
  const int aoff = nl*272 + kq*32;
  const int woff = kq*272 + cc;
  const ptrdiff_t gustep = dir ? -2048 : 2048;     // uints per t-step
  const unsigned* gubase =
      (const unsigned*)(gxd + (size_t)(dir ? (SS-1) : 0)*4096 + cc*4 + (kq & ~1));
  unsigned short* hstore =
      hbuf + (size_t)(dir ? (SS-1) : 1)*BB*HH + (size_t)(bg*4 + kq)*HH + cc;
  const ptrdiff_t hstep = (dir ? -(ptrdiff_t)1 : (ptrdiff_t)1)*BB*HH;
  const int hiSel = (kq & 1) ? 16 : 0;

  int sclear_reg = 0;

  // pre-loop: ensure steps 0,1 produced
  {
    if (tid == 0){
      int c = 0, guard = 0;
      while (c < 2){
        int j = c >> 1;
        int fi = dir ? (255 - j) : j;
        if (__hip_atomic_load(&flg[fi], __ATOMIC_RELAXED, __HIP_MEMORY_SCOPE_AGENT) >= 4u) c += 2;
        else { __builtin_amdgcn_s_sleep(8); if (++guard > (1 << 22)) { c = 2; break; } }
      }
      int lim = 64;
      while (c < lim){
        int j = c >> 1;
        int fi = dir ? (255 - j) : j;
        if (__hip_atomic_load(&flg[fi], __ATOMIC_RELAXED, __HIP_MEMORY_SCOPE_AGENT) >= 4u) c += 2;
        else break;
      }
      *s_clear = c;
    }
    __syncthreads();
    sclear_reg = *s_clear;
  }

  unsigned short gxc[4], gxn[4];
#pragma unroll
  for (int g = 0; g < 4; ++g){
    unsigned u = __hip_atomic_load(gubase + g*512, __ATOMIC_RELAXED, __HIP_MEMORY_SCOPE_AGENT);
    gxc[g] = (unsigned short)(u >> hiSel);
  }

  for (int s = 0; s < SS; ++s){
    // ensure production through step s+1 (covers this step's prefetch)
    if (sclear_reg < s + 2){
      if (tid == 0){
        int c = *s_clear, guard = 0;
        int tgt = s + 2; if (tgt > SS) tgt = SS;
        while (c < tgt){
          int j = c >> 1;
          int fi = dir ? (255 - j) : j;
          if (__hip_atomic_load(&flg[fi], __ATOMIC_RELAXED, __HIP_MEMORY_SCOPE_AGENT) >= 4u) c += 2;
          else { __builtin_amdgcn_s_sleep(8); if (++guard > (1 << 22)) { c = tgt; break; } }
        }
        int lim = s + 64; if (lim > SS) lim = SS;
        while (c < lim){
          int j = c >> 1;
          int fi = dir ? (255 - j) : j;
          if (__hip_atomic_load(&flg[fi], __ATOMIC_RELAXED, __HIP_MEMORY_SCOPE_AGENT) >= 4u) c += 2;
          else break;
        }
        *s_clear = c;
      }
      __syncthreads();
      sclear_reg = *s_clear;
    }

    // prefetch next-step gx (sc1, retires under MFMA)
    const unsigned* gun = (s + 1 < SS) ? (gubase + gustep) : gubase;
#pragma unroll
    for (int g = 0; g < 4; ++g){
      unsigned u = __hip_atomic_load(gun + g*512, __ATOMIC_RELAXED, __HIP_MEMORY_SCOPE_AGENT);
      gxn[g] = (unsigned short)(u >> hiSel);
    }

    // A-fragments: 2 insts x 32B contiguous from linear fp8 tile
    const unsigned char* tp8 = h8b + (s & 1)*4352 + aoff;
    i32x8 af0, af1;
    {
      i32x4 lo = *(const i32x4*)(tp8);
      i32x4 hi = *(const i32x4*)(tp8 + 16);
      af0 = (i32x8){lo[0],lo[1],lo[2],lo[3],hi[0],hi[1],hi[2],hi[3]};
      i32x4 lo2 = *(const i32x4*)(tp8 + 128);
      i32x4 hi2 = *(const i32x4*)(tp8 + 144);
      af1 = (i32x8){lo2[0],lo2[1],lo2[2],lo2[3],hi2[0],hi2[1],hi2[2],hi2[3]};
    }

    f32x4 acc[4];
#pragma unroll
    for (int g = 0; g < 4; ++g) acc[g] = (f32x4){0.f,0.f,0.f,0.f};
#pragma unroll
    for (int g = 0; g < 4; ++g)
      acc[g] = __builtin_amdgcn_mfma_scale_f32_16x16x128_f8f6f4(
                 af0, wB[g][0], acc[g], 0, 0, 0, 0x7F7F7F7F, 0, 0x7F7F7F7F);
#pragma unroll
    for (int g = 0; g < 4; ++g)
      acc[g] = __builtin_amdgcn_mfma_scale_f32_16x16x128_f8f6f4(
                 af1, wB[g][1], acc[g], 0, 0, 0, 0x7F7F7F7F, 0, 0x7F7F7F7F);

    // intra-wave gate exchange (kq==0 lanes hold batch rows 0-3)
    if (kq == 0){
#pragma unroll
      for (int g = 0; g < 4; ++g)
        *(f32x4*)&xch[w][g][nl][0] = acc[g];
    }
    asm volatile("s_waitcnt lgkmcnt(0)" ::: "memory");

    // combine: lane (batch kq, col cc)
    {
      float i_ = xch[w][0][nl][kq]*ISC + bf2f(gxc[0]);
      float f_ = xch[w][1][nl][kq]*ISC + bf2f(gxc[1]);
      float g_ = xch[w][2][nl][kq]*ISC + bf2f(gxc[2]);
      float o_ = xch[w][3][nl][kq]*ISC + bf2f(gxc[3]);
      float cn = sigm(f_)*c0 + sigm(i_)*ftanh(g_);
      c0 = cn;
      float h = sigm(o_)*ftanh(cn);

      float s1 = __shfl_xor(h, 1);
      unsigned short p01 = cvt2fp8(h*HSC, s1*HSC);
      unsigned p23 = __shfl_xor((unsigned)p01, 2);
      if ((nl & 3) == 0){
        unsigned word = (unsigned)p01 | (p23 << 16);
        *(unsigned*)(h8b + ((s + 1) & 1)*4352 + woff) = word;
      }
      if (!(nl & 1)){
        unsigned hv;
        asm volatile("v_cvt_pk_bf16_f32 %0, %1, %2" : "=v"(hv) : "v"(h), "v"(s1));
        *(unsigned*)hstore = hv;
      }
    }

#pragma unroll
    for (int g = 0; g < 4; ++g) gxc[g] = gxn[g];
    gubase = gun;
    hstore += hstep;

    asm volatile("s_waitcnt lgkmcnt(0)" ::: "memory");
    __builtin_amdgcn_s_barrier();
    asm volatile("" ::: "memory");
  }
}

// ---------------- FC via MFMA, LDS-staged A ----------------
__global__ __launch_bounds__(256,1) void k_fc(
    const unsigned short* __restrict__ hf, const unsigned short* __restrict__ hb,
    const float* __restrict__ fcW, const float* __restrict__ fcb,
    float* __restrict__ logits)
{
  __shared__ unsigned short Bs[32][516];
  __shared__ unsigned short Ah[4][32][260];
  __shared__ float fcb_s[32];
  const int tid = threadIdx.x;
  for (int i = tid; i < 32*512; i += 256){
    int tg = i >> 9, k = i & 511;
    Bs[tg][k] = f2bf(fcW[tg*512 + k]);
  }
  if (tid < 32) fcb_s[tid] = fcb[tid];
  __syncthreads();

  const int lane = tid & 63, w = tid >> 6;
  const int nl = lane & 15, kq = lane >> 4;
  const int pbase = blockIdx.x * 128;

  f32x4 acc[2][2];
#pragma unroll
  for (int mt = 0; mt < 2; ++mt)
#pragma unroll
    for (int nt = 0; nt < 2; ++nt) acc[mt][nt] = (f32x4){0.f,0.f,0.f,0.f};

  for (int half = 0; half < 2; ++half){
    for (int rr = 0; rr < 32; ++rr){
      int p = pbase + w*32 + rr;
      int t = p >> 6, b = p & 63;
      const unsigned short* src = half ? (hb + (size_t)(t*BB + b)*HH)
                                       : (hf + (size_t)((t+1)*BB + b)*HH);
      *(uint2*)&Ah[w][rr][lane*4] = *(const uint2*)(src + lane*4);
    }
#pragma unroll
    for (int kt = 0; kt < 8; ++kt){
      int kl = kt*32 + kq*4;
      bf16x8 a[2];
#pragma unroll
      for (int mt = 0; mt < 2; ++mt){
        const unsigned short* ar = &Ah[w][mt*16 + nl][kl];
        short4v lo = *(const short4v*)ar;
        short4v hi = *(const short4v*)(ar + 16);
        bf16x8 f = {lo[0],lo[1],lo[2],lo[3],hi[0],hi[1],hi[2],hi[3]};
        a[mt] = f;
      }
#pragma unroll
      for (int nt = 0; nt < 2; ++nt){
        const unsigned short* br = &Bs[nt*16 + nl][half*256 + kl];
        short4v lo = *(const short4v*)br;
        short4v hi = *(const short4v*)(br + 16);
        bf16x8 bv = {lo[0],lo[1],lo[2],lo[3],hi[0],hi[1],hi[2],hi[3]};
        acc[0][nt] = __builtin_amdgcn_mfma_f32_16x16x32_bf16(a[0], bv, acc[0][nt], 0,0,0);
        acc[1][nt] = __builtin_amdgcn_mfma_f32_16x16x32_bf16(a[1], bv, acc[1][nt], 0,0,0);
      }
    }
  }
#pragma unroll
  for (int mt = 0; mt < 2; ++mt)
#pragma unroll
    for (int nt = 0; nt < 2; ++nt)
#pragma unroll
      for (int r = 0; r < 4; ++r){
        int p = pbase + w*32 + mt*16 + kq*4 + r;
        int tg = nt*16 + nl;
        logits[(size_t)p*TT + tg] = acc[mt][nt][r] + fcb_s[tg];
      }
}

// ---------------- merged CRF: blocks 0-15 den, 16-31 vit (LDS hist), 32-47 num ----------------
__global__ void k_crf(const float* __restrict__ logits, const int* __restrict__ mask,
                      const int* __restrict__ labels,
                      const float* __restrict__ start, const float* __restrict__ endt,
                      const float* __restrict__ trans,
                      float* __restrict__ den, float* __restrict__ num,
                      float* __restrict__ preds)
{
  __shared__ float tr[1024];
  __shared__ unsigned char vh_l[4][SS-1][32];
  const int tid = threadIdx.x;
  const int role = blockIdx.x >> 4;
  const int bq   = blockIdx.x & 15;
  if (role != 2){
    for (int i = tid; i < 1024; i += 256) tr[i] = trans[i];
    __syncthreads();
  }
  const int lane = tid & 63, w = tid >> 6;
  const int b = bq*4 + w;
  const int grp = lane >> 5, tp = lane & 31;

  if (role == 0){
    float score = start[tp] + logits[(size_t)b*TT + tp];
    float em_c = logits[(size_t)(BB + b)*TT + tp];
    int   mk_c = mask[b*SS + 1];
    for (int s = 1; s < SS; ++s){
      int sn = (s + 1 < SS) ? s + 1 : s;
      float em_n = logits[(size_t)(sn*BB + b)*TT + tp];
      int   mk_n = mask[b*SS + sn];
      float m = -1e30f;
#pragma unroll
      for (int jj = 0; jj < 16; ++jj){
        int j = grp*16 + jj;
        float v = __shfl(score, j) + tr[j*32 + tp];
        m = fmaxf(m, v);
      }
      m = fmaxf(m, __shfl_xor(m, 32));
      float ssum = 0.f;
#pragma unroll
      for (int jj = 0; jj < 16; ++jj){
        int j = grp*16 + jj;
        float v = __shfl(score, j) + tr[j*32 + tp];
        ssum += __expf(v - m);
      }
      ssum += __shfl_xor(ssum, 32);
      float ns = m + __logf(ssum) + em_c;
      score = mk_c ? ns : score;
      em_c = em_n; mk_c = mk_n;
    }
    float v = score + endt[tp];
    float mm = v;
    for (int d = 1; d < 32; d <<= 1) mm = fmaxf(mm, __shfl_xor(mm, d));
    float se = __expf(v - mm);
    for (int d = 1; d < 32; d <<= 1) se += __shfl_xor(se, d);
    if (lane == 0) den[b] = mm + __logf(se);
  } else if (role == 1){
    float score = start[tp] + logits[(size_t)b*TT + tp];
    float em_c = logits[(size_t)(BB + b)*TT + tp];
    int   mk_c = mask[b*SS + 1];
    for (int s = 1; s < SS; ++s){
      int sn = (s + 1 < SS) ? s + 1 : s;
      float em_n = logits[(size_t)(sn*BB + b)*TT + tp];
      int   mk_n = mask[b*SS + sn];
      float m = -1e30f; int am = 0;
#pragma unroll
      for (int jj = 0; jj < 16; ++jj){
        int j = grp*16 + jj;
        float v = __shfl(score, j) + tr[j*32 + tp];
        if (v > m){ m = v; am = j; }
      }
      float om = __shfl_xor(m, 32); int oam = __shfl_xor(am, 32);
      if (om > m || (om == m && oam < am)){ m = om; am = oam; }
      float ns = m + em_c;
      int idx = mk_c ? am : tp;
      if (grp == 0) vh_l[w][s-1][tp] = (unsigned char)idx;
      score = mk_c ? ns : score;
      em_c = em_n; mk_c = mk_n;
    }
    float v = score + endt[tp]; int a = tp;
    for (int d = 1; d < 32; d <<= 1){
      float ov = __shfl_xor(v, d); int oa = __shfl_xor(a, d);
      if (ov > v || (ov == v && oa < a)){ v = ov; a = oa; }
    }
    int tag = __shfl(a, 0);
    if (lane == 0) preds[(size_t)b*SS + SS - 1] = (float)tag;
    for (int s = SS - 1; s >= 1; --s){
      int rv = vh_l[w][s-1][tp];
      int pv = __shfl(rv, tag);
      if (lane == 0) preds[(size_t)b*SS + s - 1] = (float)pv;
      tag = pv;
    }
  } else {
    float acc = 0.f; int mcnt = 0;
    for (int s = lane; s < SS; s += 64){
      int mk = mask[b*SS + s];
      mcnt += mk;
      if (s >= 1){
        int tg = labels[b*SS + s], tpp = labels[b*SS + s - 1];
        float v = trans[tpp*32 + tg] + logits[(size_t)(s*BB + b)*TT + tg];
        acc += mk ? v : 0.f;
      }
    }
    for (int d = 1; d < 64; d <<= 1){ acc += __shfl_xor(acc, d); mcnt += __shfl_xor(mcnt, d); }
    if (lane == 0){
      int t0 = labels[b*SS];
      int tl = labels[b*SS + (mcnt - 1)];
      num[b] = start[t0] + logits[(size_t)b*TT + t0] + acc + endt[tl];
    }
  }
}

// ---------------- loss ----------------
__global__ void k_loss(const float* __restrict__ num, const float* __restrict__ den,
                       float* __restrict__ out)
{
  int l = threadIdx.x;
  float v = num[l] - den[l];
  for (int d = 1; d < 64; d <<= 1) v += __shfl_xor(v, d);
  if (l == 0) out[BB*SS] = -v;
}

extern "C" void kernel_launch(void* const* d_in, const int* in_sizes, int n_in,
                              void* d_out, int out_size, void* d_ws, size_t ws_size,
                              hipStream_t stream)
{
  const int*   seq       = (const int*)  d_in[0];
  const int*   mask      = (const int*)  d_in[1];
  const int*   labels    = (const int*)  d_in[2];
  const float* embedding = (const float*)d_in[3];
  const float* Wih_f     = (const float*)d_in[4];
  const float* Whh_f     = (const float*)d_in[5];
  const float* bih_f     = (const float*)d_in[6];
  const float* bhh_f     = (const float*)d_in[7];
  const float* Wih_b     = (const float*)d_in[8];
  const float* Whh_b     = (const float*)d_in[9];
  const float* bih_b     = (const float*)d_in[10];
  const float* bhh_b     = (const float*)d_in[11];
  const float* fcW       = (const float*)d_in[12];
  const float* fcb       = (const float*)d_in[13];
  const float* start_t   = (const float*)d_in[14];
  const float* end_t     = (const float*)d_in[15];
  const float* trans     = (const float*)d_in[16];

  char* ws = (char*)d_ws;
  size_t off = 0;
  unsigned short* gxb = (unsigned short*)(ws + off); off += (size_t)2*SS*1024*64*2;     // 128 MiB
  unsigned short* hf  = (unsigned short*)(ws + off); off += (size_t)(SS+1)*BB*HH*2;     // 16 MiB
  unsigned short* hb  = (unsigned short*)(ws + off); off += (size_t)(SS+1)*BB*HH*2;     // 16 MiB
  float*          lgt = (float*)(ws + off);          off += (size_t)SS*BB*TT*4;         // 4 MiB
  float*          den = (float*)(ws + off);          off += 256;
  float*          num = (float*)(ws + off);          off += 256;
  unsigned int*   flg = (unsigned int*)(ws + off);   off += 2*256*4;                    // 2 KiB

  hipMemsetAsync(flg, 0, 2*256*4, stream);

  k_fused<<<2080, 1024, 0, stream>>>(seq, embedding, Wih_f, Wih_b,
                                     bih_f, bhh_f, bih_b, bhh_b,
                                     Whh_f, Whh_b, gxb, hf, hb, flg);
  k_fc<<<256, 256, 0, stream>>>(hf, hb, fcW, fcb, lgt);
  k_crf<<<48, 256, 0, stream>>>(lgt, mask, labels, start_t, end_t, trans, den, num, (float*)d_out);
  k_loss<<<1, 64, 0, stream>>>(num, den, (float*)d_out);
}